// Round 10
// baseline (276.234 us; speedup 1.0000x reference)
//
#include <hip/hip_runtime.h>
#include <hip/hip_bf16.h>
#include <math.h>

#define NREG 90
#define NN 91
#define JROWS 96
#define STR 100           // fp32 A LDS stride (words); bank stride 4 -> worst 2-way
#define NPAIR 4005
#define H1 256
#define H2 256
#define F1 128

// frag region: per graph 18 (m,ks) groups x (hi 512 + lo 512) bf16 = 18432 elems = 36864 B
#define FRAG_ELEMS_PG 18432
#define AROW_FLOATS 96

typedef __bf16 bf16x8 __attribute__((ext_vector_type(8)));
typedef float  f32x4  __attribute__((ext_vector_type(4)));
typedef unsigned int u32x4v __attribute__((ext_vector_type(4)));

__device__ __forceinline__ unsigned int pack_hl(float f) {
    __bf16 h = (__bf16)f;
    __bf16 l = (__bf16)(f - (float)h);
    unsigned short hb = __builtin_bit_cast(unsigned short, h);
    unsigned short lb = __builtin_bit_cast(unsigned short, l);
    return ((unsigned int)lb << 16) | (unsigned int)hb;
}

// ---- one-shot prep: W fragments (MFMA B-operand layout, hi/lo) + pair table ----
__global__ void prep(const float* __restrict__ W1, __bf16* __restrict__ Whi,
                     __bf16* __restrict__ Wlo, int* __restrict__ ptab) {
    int t = blockIdx.x * 256 + threadIdx.x;       // 0..24575
    {
        int e  = t & 7;
        int ln = (t >> 3) & 63;
        int g  = t >> 9;
        int nt = g / 3;
        int ks = g - nt * 3;
        int h = nt * 16 + (ln & 15);
        int k = ks * 32 + (ln >> 4) * 8 + e;
        float v = (k < NN) ? W1[h * NN + k] : 0.0f;
        __bf16 hb = (__bf16)v;
        __bf16 lb = (__bf16)(v - (float)hb);
        Whi[t] = hb;
        Wlo[t] = lb;
    }
    if (t < NPAIR) {
        float disc = 32041.0f - 8.0f * (float)t;
        int i = (int)floorf((179.0f - sqrtf(disc)) * 0.5f);
        if (i < 0) i = 0;
        while (i > 0 && t < i * (179 - i) / 2) --i;
        while (t >= (i + 1) * (178 - i) / 2) ++i;
        int j = i + 1 + (t - i * (179 - i) / 2);
        ptab[t] = (i << 7) | j;
    }
}

// ================= kernel 1: build A_hat, emit MFMA-ready fragments =================
__global__ __launch_bounds__(256)
void k1_build(const float* __restrict__ coh,     // [n, 4005] (chunk-offset)
              const int*   __restrict__ ptab,
              __bf16*      __restrict__ Afrag,   // [n][18432]
              float*       __restrict__ arowg)   // [n][96]
{
    __shared__ __align__(16) float A[JROWS * STR];   // 38400 B
    __shared__ __align__(16) float dinv[128];

    const int b = blockIdx.x;
    const int t = threadIdx.x;
    const float* cb = coh + (size_t)b * NPAIR;

    // ---- 1) zero A + dinv ----
    for (int m = t; m < JROWS * (STR / 4); m += 256)
        ((float4*)A)[m] = make_float4(0.f, 0.f, 0.f, 0.f);
    if (t < 128) dinv[t] = 0.0f;
    __syncthreads();

    // ---- 2) scatter + supernode + identity ----
    for (int m = t; m < NPAIR; m += 256) {
        int p = ptab[m];
        int i = p >> 7, j = p & 127;
        float v = cb[m];
        A[i * STR + j] = v;
        A[j * STR + i] = v;
    }
    if (t < NN) {
        A[t * STR + t] = 1.0f;
        if (t < NREG) {
            A[NREG * STR + t] = 1.0f;
            A[t * STR + NREG] = 1.0f;
        }
    }
    __syncthreads();

    // ---- 3) degree^-1/2 ----
    if (t < NN) {
        const float4* row = (const float4*)&A[t * STR];
        float sx = 0.f, sy = 0.f, sz = 0.f, sw = 0.f;
        #pragma unroll
        for (int q = 0; q < STR / 4; ++q) {
            float4 v = row[q];
            sx += v.x; sy += v.y; sz += v.z; sw += v.w;
        }
        dinv[t] = 1.0f / sqrtf((sx + sy) + (sz + sw));
    }
    __syncthreads();

    // ---- 4) fused scale + hi/lo split + fragment store (reads LDS, writes global) ----
    {
        const int w = t >> 6, lane = t & 63;
        const int lrow = lane & 15, lkg = lane >> 4;
        __bf16* frag_g = Afrag + (size_t)b * FRAG_ELEMS_PG;

        for (int g = w; g < 18; g += 4) {
            int m = g / 3, ks = g - m * 3;
            int row = m * 16 + lrow;
            int cb2 = ks * 32 + lkg * 8;
            float dr = dinv[row];
            float4 f0 = *(const float4*)&A[row * STR + cb2];
            float4 f1 = *(const float4*)&A[row * STR + cb2 + 4];
            float4 d0 = *(const float4*)&dinv[cb2];
            float4 d1 = *(const float4*)&dinv[cb2 + 4];
            float v0 = f0.x * dr * d0.x, v1 = f0.y * dr * d0.y;
            float v2 = f0.z * dr * d0.z, v3 = f0.w * dr * d0.w;
            float v4 = f1.x * dr * d1.x, v5 = f1.y * dr * d1.y;
            float v6 = f1.z * dr * d1.z, v7 = f1.w * dr * d1.w;
            bf16x8 hh, ll;
            hh[0] = (__bf16)v0; ll[0] = (__bf16)(v0 - (float)hh[0]);
            hh[1] = (__bf16)v1; ll[1] = (__bf16)(v1 - (float)hh[1]);
            hh[2] = (__bf16)v2; ll[2] = (__bf16)(v2 - (float)hh[2]);
            hh[3] = (__bf16)v3; ll[3] = (__bf16)(v3 - (float)hh[3]);
            hh[4] = (__bf16)v4; ll[4] = (__bf16)(v4 - (float)hh[4]);
            hh[5] = (__bf16)v5; ll[5] = (__bf16)(v5 - (float)hh[5]);
            hh[6] = (__bf16)v6; ll[6] = (__bf16)(v6 - (float)hh[6]);
            hh[7] = (__bf16)v7; ll[7] = (__bf16)(v7 - (float)hh[7]);
            *(bf16x8*)(frag_g + (size_t)g * 1024 + lane * 8)       = hh;
            *(bf16x8*)(frag_g + (size_t)g * 1024 + 512 + lane * 8) = ll;
        }
        // arow = scaled row 90 (fp32)
        if (t < 24) {
            int c4 = t * 4;
            float4 f = *(const float4*)&A[NREG * STR + c4];
            float4 d = *(const float4*)&dinv[c4];
            float dr = dinv[NREG];
            float4 o;
            o.x = f.x * dr * d.x; o.y = f.y * dr * d.y;
            o.z = f.z * dr * d.z; o.w = f.w * dr * d.w;
            *(float4*)&arowg[(size_t)b * AROW_FLOATS + c4] = o;
        }
    }
}

// ================= kernel 2: MFMA GEMM + pooled + MLP tail =================
__global__ __launch_bounds__(512)
void k2_gemm(const __bf16* __restrict__ Afrag,   // [n][18432]
             const float*  __restrict__ arowg,   // [n][96]
             const __bf16* __restrict__ Whi,     // [16][3][64][8]
             const __bf16* __restrict__ Wlo,
             const float*  __restrict__ W2,
             const float*  __restrict__ Wo1,
             const float*  __restrict__ bo1,
             const float*  __restrict__ Wo2,
             const float*  __restrict__ bo2,
             float*        __restrict__ out)
{
    __shared__ __align__(16) float svec[H1];
    __shared__ __align__(16) float pooled[H2];
    __shared__ __align__(16) float fc1[F1];

    const int b = blockIdx.x;
    const int t = threadIdx.x;
    const int w = t >> 6, lane = t & 63;
    const int lrow = lane & 15, lkg = lane >> 4;

    // ---- MFMA stage: wave w owns n-tiles {2w, 2w+1} ----
    {
        const __bf16* frag_g = Afrag + (size_t)b * FRAG_ELEMS_PG;
        const float*  arow_g = arowg + (size_t)b * AROW_FLOATS;

        bf16x8 whi_r[2][3], wlo_r[2][3];
        #pragma unroll
        for (int nt = 0; nt < 2; ++nt)
            #pragma unroll
            for (int ks = 0; ks < 3; ++ks) {
                int idx = (((w * 2 + nt) * 3 + ks) * 64 + lane) * 8;
                whi_r[nt][ks] = *(const bf16x8*)(Whi + idx);
                wlo_r[nt][ks] = *(const bf16x8*)(Wlo + idx);
            }

        float sp[2] = {0.f, 0.f};

        #pragma unroll 1
        for (int m = 0; m < 6; ++m) {
            bf16x8 ahi[3], alo[3];
            #pragma unroll
            for (int ks = 0; ks < 3; ++ks) {
                const __bf16* p = frag_g + (size_t)(m * 3 + ks) * 1024 + lane * 8;
                ahi[ks] = *(const bf16x8*)p;
                alo[ks] = *(const bf16x8*)(p + 512);
            }
            float aj[4];
            #pragma unroll
            for (int ri = 0; ri < 4; ++ri)
                aj[ri] = arow_g[m * 16 + lkg * 4 + ri];

            f32x4 acc[2];
            acc[0] = (f32x4){0.f, 0.f, 0.f, 0.f};
            acc[1] = (f32x4){0.f, 0.f, 0.f, 0.f};
            #pragma unroll
            for (int ks = 0; ks < 3; ++ks) {
                #pragma unroll
                for (int nt = 0; nt < 2; ++nt) {
                    acc[nt] = __builtin_amdgcn_mfma_f32_16x16x32_bf16(ahi[ks], whi_r[nt][ks], acc[nt], 0, 0, 0);
                    acc[nt] = __builtin_amdgcn_mfma_f32_16x16x32_bf16(ahi[ks], wlo_r[nt][ks], acc[nt], 0, 0, 0);
                    acc[nt] = __builtin_amdgcn_mfma_f32_16x16x32_bf16(alo[ks], whi_r[nt][ks], acc[nt], 0, 0, 0);
                }
            }
            #pragma unroll
            for (int nt = 0; nt < 2; ++nt)
                #pragma unroll
                for (int ri = 0; ri < 4; ++ri)
                    sp[nt] = fmaf(aj[ri], fmaxf(acc[nt][ri], 0.f), sp[nt]);
        }

        #pragma unroll
        for (int nt = 0; nt < 2; ++nt) {
            float s = sp[nt];
            s += __shfl_xor(s, 16);
            s += __shfl_xor(s, 32);
            if (lane < 16) svec[(w * 2 + nt) * 16 + lrow] = s;
        }
    }
    __syncthreads();

    // ---- pooled[g] = sum_h W2[g,h] * s[h] ----
    if (t < H2) {
        const float* w2r = W2 + t * H1;
        float p0 = 0.f, p1 = 0.f, p2 = 0.f, p3 = 0.f;
        #pragma unroll 8
        for (int qq = 0; qq < H1 / 4; ++qq) {
            float4 sv = ((const float4*)svec)[qq];
            float4 wv4 = *(const float4*)&w2r[qq * 4];
            p0 = fmaf(sv.x, wv4.x, p0);
            p1 = fmaf(sv.y, wv4.y, p1);
            p2 = fmaf(sv.z, wv4.z, p2);
            p3 = fmaf(sv.w, wv4.w, p3);
        }
        pooled[t] = (p0 + p1) + (p2 + p3);
    }
    __syncthreads();

    // ---- fc1 = relu(Wo1 @ pooled + bo1) ----
    if (t < F1) {
        const float* wo1r = Wo1 + t * H2;
        float p0 = bo1[t], p1 = 0.f, p2 = 0.f, p3 = 0.f;
        #pragma unroll 8
        for (int qq = 0; qq < H2 / 4; ++qq) {
            float4 pv = ((const float4*)pooled)[qq];
            float4 wv4 = *(const float4*)&wo1r[qq * 4];
            p0 = fmaf(pv.x, wv4.x, p0);
            p1 = fmaf(pv.y, wv4.y, p1);
            p2 = fmaf(pv.z, wv4.z, p2);
            p3 = fmaf(pv.w, wv4.w, p3);
        }
        fc1[t] = fmaxf((p0 + p1) + (p2 + p3), 0.f);
    }
    __syncthreads();

    // ---- out = Wo2 @ fc1 + bo2 ----
    if (t < 64) {
        int o = t & 1;
        int f0 = t >> 1;
        const float* wo2r = Wo2 + o * F1;
        float p = 0.f;
        #pragma unroll
        for (int s = 0; s < 4; ++s)
            p = fmaf(wo2r[f0 + 32 * s], fc1[f0 + 32 * s], p);
        p += __shfl_xor(p, 2);
        p += __shfl_xor(p, 4);
        p += __shfl_xor(p, 8);
        p += __shfl_xor(p, 16);
        p += __shfl_xor(p, 32);
        if (t < 2) out[(size_t)b * 2 + t] = p + bo2[t];
    }
}

// ================= fallback: R9 monolithic kernel (ws too small) =================
__global__ __launch_bounds__(256)
void gcn_mono(const float* __restrict__ coh, const __bf16* __restrict__ Whi,
              const __bf16* __restrict__ Wlo, const int* __restrict__ ptab,
              const float* __restrict__ W2, const float* __restrict__ Wo1,
              const float* __restrict__ bo1, const float* __restrict__ Wo2,
              const float* __restrict__ bo2, float* __restrict__ out)
{
    __shared__ __align__(16) float A[JROWS * STR];
    __shared__ __align__(16) float svec_fc1[H1];
    __shared__ __align__(16) float pooled_dinv[H2];
    __shared__ __align__(16) float arow[96];
    float* dinv = pooled_dinv;
    float* pooled = pooled_dinv;
    const int b = blockIdx.x;
    const int t = threadIdx.x;
    const float* cb = coh + (size_t)b * NPAIR;

    for (int m = t; m < JROWS * 24; m += 256) {
        int i = m / 24, g = m - i * 24;
        *(float4*)&A[i * STR + g * 4] = make_float4(0.f, 0.f, 0.f, 0.f);
    }
    __syncthreads();
    for (int m = t; m < NPAIR; m += 256) {
        int p = ptab[m];
        int i = p >> 7, j = p & 127;
        float v = cb[m];
        A[i * STR + j] = v;
        A[j * STR + i] = v;
    }
    if (t < NN) {
        A[t * STR + t] = 1.0f;
        if (t < NREG) { A[NREG * STR + t] = 1.0f; A[t * STR + NREG] = 1.0f; }
    }
    __syncthreads();
    if (t < 256) dinv[t] = 0.0f;
    __syncthreads();
    if (t < NN) {
        const float4* row = (const float4*)&A[t * STR];
        float sx = 0.f, sy = 0.f, sz = 0.f, sw = 0.f;
        #pragma unroll
        for (int q = 0; q < 24; ++q) { float4 v = row[q]; sx += v.x; sy += v.y; sz += v.z; sw += v.w; }
        dinv[t] = 1.0f / sqrtf((sx + sy) + (sz + sw));
    }
    __syncthreads();
    for (int m = t; m < JROWS * 24; m += 256) {
        int i = m / 24;
        int c4 = (m - i * 24) * 4;
        float di = dinv[i];
        float4 dj = *(const float4*)&dinv[c4];
        float4 v = *(float4*)&A[i * STR + c4];
        v.x *= di * dj.x; v.y *= di * dj.y; v.z *= di * dj.z; v.w *= di * dj.w;
        *(float4*)&A[i * STR + c4] = v;
        if (i == NREG) *(float4*)&arow[c4] = v;
    }
    __syncthreads();
    for (int m = t; m < JROWS * 24; m += 256) {
        int i = m / 24;
        int c4 = (m - i * 24) * 4;
        float4 v = *(float4*)&A[i * STR + c4];
        uint4 p;
        p.x = pack_hl(v.x); p.y = pack_hl(v.y); p.z = pack_hl(v.z); p.w = pack_hl(v.w);
        *(uint4*)&A[i * STR + c4] = p;
    }
    __syncthreads();
    {
        const int w = t >> 6, lane = t & 63;
        const int lrow = lane & 15, lkg = lane >> 4;
        const unsigned int* Au = (const unsigned int*)A;
        bf16x8 whi_r[4][3], wlo_r[4][3];
        #pragma unroll
        for (int nt = 0; nt < 4; ++nt)
            #pragma unroll
            for (int ks = 0; ks < 3; ++ks) {
                int idx = (((w * 4 + nt) * 3 + ks) * 64 + lane) * 8;
                whi_r[nt][ks] = *(const bf16x8*)(Whi + idx);
                wlo_r[nt][ks] = *(const bf16x8*)(Wlo + idx);
            }
        float sp[4] = {0.f, 0.f, 0.f, 0.f};
        #pragma unroll 1
        for (int m = 0; m < 6; ++m) {
            bf16x8 ahi[3], alo[3];
            #pragma unroll
            for (int ks = 0; ks < 3; ++ks) {
                const uint4* src = (const uint4*)(Au + (m * 16 + lrow) * STR + ks * 32 + lkg * 8);
                uint4 a0 = src[0];
                uint4 a1 = src[1];
                u32x4v hw, lw;
                hw[0] = __builtin_amdgcn_perm(a0.y, a0.x, 0x05040100u);
                hw[1] = __builtin_amdgcn_perm(a0.w, a0.z, 0x05040100u);
                hw[2] = __builtin_amdgcn_perm(a1.y, a1.x, 0x05040100u);
                hw[3] = __builtin_amdgcn_perm(a1.w, a1.z, 0x05040100u);
                lw[0] = __builtin_amdgcn_perm(a0.y, a0.x, 0x07060302u);
                lw[1] = __builtin_amdgcn_perm(a0.w, a0.z, 0x07060302u);
                lw[2] = __builtin_amdgcn_perm(a1.y, a1.x, 0x07060302u);
                lw[3] = __builtin_amdgcn_perm(a1.w, a1.z, 0x07060302u);
                ahi[ks] = __builtin_bit_cast(bf16x8, hw);
                alo[ks] = __builtin_bit_cast(bf16x8, lw);
            }
            float aj[4];
            #pragma unroll
            for (int ri = 0; ri < 4; ++ri) aj[ri] = arow[m * 16 + lkg * 4 + ri];
            f32x4 acc[4];
            #pragma unroll
            for (int nt = 0; nt < 4; ++nt) acc[nt] = (f32x4){0.f, 0.f, 0.f, 0.f};
            #pragma unroll
            for (int ks = 0; ks < 3; ++ks)
                #pragma unroll
                for (int nt = 0; nt < 4; ++nt) {
                    acc[nt] = __builtin_amdgcn_mfma_f32_16x16x32_bf16(ahi[ks], whi_r[nt][ks], acc[nt], 0, 0, 0);
                    acc[nt] = __builtin_amdgcn_mfma_f32_16x16x32_bf16(ahi[ks], wlo_r[nt][ks], acc[nt], 0, 0, 0);
                    acc[nt] = __builtin_amdgcn_mfma_f32_16x16x32_bf16(alo[ks], whi_r[nt][ks], acc[nt], 0, 0, 0);
                }
            #pragma unroll
            for (int nt = 0; nt < 4; ++nt)
                #pragma unroll
                for (int ri = 0; ri < 4; ++ri)
                    sp[nt] = fmaf(aj[ri], fmaxf(acc[nt][ri], 0.f), sp[nt]);
        }
        __syncthreads();
        #pragma unroll
        for (int nt = 0; nt < 4; ++nt) {
            float s = sp[nt];
            s += __shfl_xor(s, 16);
            s += __shfl_xor(s, 32);
            if (lane < 16) svec_fc1[(w * 4 + nt) * 16 + lrow] = s;
        }
    }
    __syncthreads();
    {
        const float* w2r = W2 + t * H1;
        float p0 = 0.f, p1 = 0.f, p2 = 0.f, p3 = 0.f;
        #pragma unroll 8
        for (int qq = 0; qq < H1 / 4; ++qq) {
            float4 sv = ((const float4*)svec_fc1)[qq];
            float4 wv4 = *(const float4*)&w2r[qq * 4];
            p0 = fmaf(sv.x, wv4.x, p0); p1 = fmaf(sv.y, wv4.y, p1);
            p2 = fmaf(sv.z, wv4.z, p2); p3 = fmaf(sv.w, wv4.w, p3);
        }
        float pr = (p0 + p1) + (p2 + p3);
        __syncthreads();
        pooled[t] = pr;
    }
    __syncthreads();
    {
        float fr = 0.f;
        if (t < F1) {
            const float* wo1r = Wo1 + t * H2;
            float p0 = bo1[t], p1 = 0.f, p2 = 0.f, p3 = 0.f;
            #pragma unroll 8
            for (int qq = 0; qq < H2 / 4; ++qq) {
                float4 pv = ((const float4*)pooled)[qq];
                float4 wv4 = *(const float4*)&wo1r[qq * 4];
                p0 = fmaf(pv.x, wv4.x, p0); p1 = fmaf(pv.y, wv4.y, p1);
                p2 = fmaf(pv.z, wv4.z, p2); p3 = fmaf(pv.w, wv4.w, p3);
            }
            fr = fmaxf((p0 + p1) + (p2 + p3), 0.f);
        }
        __syncthreads();
        if (t < F1) svec_fc1[t] = fr;
    }
    __syncthreads();
    if (t < 64) {
        int o = t & 1;
        int f0 = t >> 1;
        const float* wo2r = Wo2 + o * F1;
        float p = 0.f;
        #pragma unroll
        for (int s = 0; s < 4; ++s) p = fmaf(wo2r[f0 + 32 * s], svec_fc1[f0 + 32 * s], p);
        p += __shfl_xor(p, 2); p += __shfl_xor(p, 4); p += __shfl_xor(p, 8);
        p += __shfl_xor(p, 16); p += __shfl_xor(p, 32);
        if (t < 2) out[(size_t)b * 2 + t] = p + bo2[t];
    }
}

extern "C" void kernel_launch(void* const* d_in, const int* in_sizes, int n_in,
                              void* d_out, int out_size, void* d_ws, size_t ws_size,
                              hipStream_t stream) {
    const float* coh = (const float*)d_in[0];
    const float* W1  = (const float*)d_in[1];
    const float* W2  = (const float*)d_in[2];
    const float* Wo1 = (const float*)d_in[3];
    const float* bo1 = (const float*)d_in[4];
    const float* Wo2 = (const float*)d_in[5];
    const float* bo2 = (const float*)d_in[6];
    float* outp = (float*)d_out;

    __bf16* Whi = (__bf16*)d_ws;                        // 49152 B
    __bf16* Wlo = Whi + 24576;                          // 49152 B
    int*    ptab = (int*)((char*)d_ws + 98304);         // 16020 B -> header ends 114688

    const int B = in_sizes[0] / NPAIR;
    prep<<<96, 256, 0, stream>>>(W1, Whi, Wlo, ptab);

    const size_t header = 114688;
    const size_t per_graph = (size_t)FRAG_ELEMS_PG * 2 + AROW_FLOATS * 4;   // 36864+384
    long cap = (ws_size > header) ? (long)((ws_size - header) / per_graph) : 0;
    if (cap > B) cap = B;

    if (cap >= 512) {
        __bf16* Afrag = (__bf16*)((char*)d_ws + header);
        float*  arowg = (float*)((char*)d_ws + header + (size_t)cap * FRAG_ELEMS_PG * 2);
        for (int off = 0; off < B; off += (int)cap) {
            int n = B - off;
            if (n > cap) n = (int)cap;
            k1_build<<<n, 256, 0, stream>>>(coh + (size_t)off * NPAIR, ptab, Afrag, arowg);
            k2_gemm<<<n, 512, 0, stream>>>(Afrag, arowg, Whi, Wlo, W2, Wo1, bo1, Wo2, bo2,
                                           outp + (size_t)off * 2);
        }
    } else {
        gcn_mono<<<B, 256, 0, stream>>>(coh, Whi, Wlo, ptab, W2, Wo1, bo1, Wo2, bo2, outp);
    }
}

// Round 11
// 243.830 us; speedup vs baseline: 1.1329x; 1.1329x over previous
//
#include <hip/hip_runtime.h>
#include <hip/hip_bf16.h>
#include <math.h>

#define NREG 90
#define NN 91
#define JROWS 96
#define STR 100           // fp32 A LDS stride (words); bank stride 4 -> worst 2-way
#define NPAIR 4005
#define H1 256
#define H2 256
#define F1 128

// frag region: per graph 18 (m,ks) groups x (hi 512 + lo 512) bf16 = 18432 elems = 36864 B
#define FRAG_ELEMS_PG 18432
#define AROW_FLOATS 96

typedef __bf16 bf16x8 __attribute__((ext_vector_type(8)));
typedef float  f32x4  __attribute__((ext_vector_type(4)));
typedef unsigned int u32x4v __attribute__((ext_vector_type(4)));

#define AS1 __attribute__((address_space(1)))
#define AS3 __attribute__((address_space(3)))

__device__ __forceinline__ unsigned int pack_hl(float f) {
    __bf16 h = (__bf16)f;
    __bf16 l = (__bf16)(f - (float)h);
    unsigned short hb = __builtin_bit_cast(unsigned short, h);
    unsigned short lb = __builtin_bit_cast(unsigned short, l);
    return ((unsigned int)lb << 16) | (unsigned int)hb;
}

// ---- one-shot prep: W fragments (MFMA B-operand layout, hi/lo) + pair table ----
__global__ void prep(const float* __restrict__ W1, __bf16* __restrict__ Whi,
                     __bf16* __restrict__ Wlo, int* __restrict__ ptab) {
    int t = blockIdx.x * 256 + threadIdx.x;       // 0..24575
    {
        int e  = t & 7;
        int ln = (t >> 3) & 63;
        int g  = t >> 9;
        int nt = g / 3;
        int ks = g - nt * 3;
        int h = nt * 16 + (ln & 15);
        int k = ks * 32 + (ln >> 4) * 8 + e;
        float v = (k < NN) ? W1[h * NN + k] : 0.0f;
        __bf16 hb = (__bf16)v;
        __bf16 lb = (__bf16)(v - (float)hb);
        Whi[t] = hb;
        Wlo[t] = lb;
    }
    if (t < NPAIR) {
        float disc = 32041.0f - 8.0f * (float)t;
        int i = (int)floorf((179.0f - sqrtf(disc)) * 0.5f);
        if (i < 0) i = 0;
        while (i > 0 && t < i * (179 - i) / 2) --i;
        while (t >= (i + 1) * (178 - i) / 2) ++i;
        int j = i + 1 + (t - i * (179 - i) / 2);
        ptab[t] = (i << 7) | j;
    }
}

// ================= kernel 1: build A_hat, emit MFMA-ready fragments =================
__global__ __launch_bounds__(256)
void k1_build(const float* __restrict__ coh,     // [n, 4005] (chunk-offset)
              const int*   __restrict__ ptab,
              __bf16*      __restrict__ Afrag,   // [n][18432]
              float*       __restrict__ arowg)   // [n][96]
{
    __shared__ __align__(16) float A[JROWS * STR];   // 38400 B
    __shared__ __align__(16) float dinv[128];

    const int b = blockIdx.x;
    const int t = threadIdx.x;
    const float* cb = coh + (size_t)b * NPAIR;

    for (int m = t; m < JROWS * (STR / 4); m += 256)
        ((float4*)A)[m] = make_float4(0.f, 0.f, 0.f, 0.f);
    if (t < 128) dinv[t] = 0.0f;
    __syncthreads();

    for (int m = t; m < NPAIR; m += 256) {
        int p = ptab[m];
        int i = p >> 7, j = p & 127;
        float v = cb[m];
        A[i * STR + j] = v;
        A[j * STR + i] = v;
    }
    if (t < NN) {
        A[t * STR + t] = 1.0f;
        if (t < NREG) {
            A[NREG * STR + t] = 1.0f;
            A[t * STR + NREG] = 1.0f;
        }
    }
    __syncthreads();

    if (t < NN) {
        const float4* row = (const float4*)&A[t * STR];
        float sx = 0.f, sy = 0.f, sz = 0.f, sw = 0.f;
        #pragma unroll
        for (int q = 0; q < STR / 4; ++q) {
            float4 v = row[q];
            sx += v.x; sy += v.y; sz += v.z; sw += v.w;
        }
        dinv[t] = 1.0f / sqrtf((sx + sy) + (sz + sw));
    }
    __syncthreads();

    {
        const int w = t >> 6, lane = t & 63;
        const int lrow = lane & 15, lkg = lane >> 4;
        __bf16* frag_g = Afrag + (size_t)b * FRAG_ELEMS_PG;

        for (int g = w; g < 18; g += 4) {
            int m = g / 3, ks = g - m * 3;
            int row = m * 16 + lrow;
            int cb2 = ks * 32 + lkg * 8;
            float dr = dinv[row];
            float4 f0 = *(const float4*)&A[row * STR + cb2];
            float4 f1 = *(const float4*)&A[row * STR + cb2 + 4];
            float4 d0 = *(const float4*)&dinv[cb2];
            float4 d1 = *(const float4*)&dinv[cb2 + 4];
            float v0 = f0.x * dr * d0.x, v1 = f0.y * dr * d0.y;
            float v2 = f0.z * dr * d0.z, v3 = f0.w * dr * d0.w;
            float v4 = f1.x * dr * d1.x, v5 = f1.y * dr * d1.y;
            float v6 = f1.z * dr * d1.z, v7 = f1.w * dr * d1.w;
            bf16x8 hh, ll;
            hh[0] = (__bf16)v0; ll[0] = (__bf16)(v0 - (float)hh[0]);
            hh[1] = (__bf16)v1; ll[1] = (__bf16)(v1 - (float)hh[1]);
            hh[2] = (__bf16)v2; ll[2] = (__bf16)(v2 - (float)hh[2]);
            hh[3] = (__bf16)v3; ll[3] = (__bf16)(v3 - (float)hh[3]);
            hh[4] = (__bf16)v4; ll[4] = (__bf16)(v4 - (float)hh[4]);
            hh[5] = (__bf16)v5; ll[5] = (__bf16)(v5 - (float)hh[5]);
            hh[6] = (__bf16)v6; ll[6] = (__bf16)(v6 - (float)hh[6]);
            hh[7] = (__bf16)v7; ll[7] = (__bf16)(v7 - (float)hh[7]);
            *(bf16x8*)(frag_g + (size_t)g * 1024 + lane * 8)       = hh;
            *(bf16x8*)(frag_g + (size_t)g * 1024 + 512 + lane * 8) = ll;
        }
        if (t < 24) {
            int c4 = t * 4;
            float4 f = *(const float4*)&A[NREG * STR + c4];
            float4 d = *(const float4*)&dinv[c4];
            float dr = dinv[NREG];
            float4 o;
            o.x = f.x * dr * d.x; o.y = f.y * dr * d.y;
            o.z = f.z * dr * d.z; o.w = f.w * dr * d.w;
            *(float4*)&arowg[(size_t)b * AROW_FLOATS + c4] = o;
        }
    }
}

// ================= kernel 2: LDS-staged MFMA GEMM + pooled + MLP tail =================
__global__ __launch_bounds__(512)
void k2_gemm(const __bf16* __restrict__ Afrag,   // [n][18432]
             const float*  __restrict__ arowg,   // [n][96]
             const __bf16* __restrict__ Whi,     // [16][3][64][8]
             const __bf16* __restrict__ Wlo,
             const float*  __restrict__ W2,
             const float*  __restrict__ Wo1,
             const float*  __restrict__ bo1,
             const float*  __restrict__ Wo2,
             const float*  __restrict__ bo2,
             float*        __restrict__ out)
{
    __shared__ __align__(16) __bf16 Al[FRAG_ELEMS_PG];  // 36864 B, same layout as Afrag
    __shared__ __align__(16) float arow_l[96];
    __shared__ __align__(16) float svec[H1];
    __shared__ __align__(16) float pooled[H2];
    __shared__ __align__(16) float fc1[F1];
    // total 39808 B

    const int b = blockIdx.x;
    const int t = threadIdx.x;
    const int w = t >> 6, lane = t & 63;
    const int lrow = lane & 15, lkg = lane >> 4;

    // ---- bulk async stage: Afrag[b] -> LDS (2304 x 16B chunks, linear both sides) ----
    {
        const __bf16* src = Afrag + (size_t)b * FRAG_ELEMS_PG;
        #pragma unroll
        for (int k = 0; k < 4; ++k) {
            int idx = k * 512 + t;
            __builtin_amdgcn_global_load_lds(
                (const AS1 unsigned int*)(src + (size_t)idx * 8),
                (AS3 unsigned int*)((char*)Al + (size_t)idx * 16), 16, 0, 0);
        }
        if (t < 256) {                      // waves 0-3, wave-uniform guard
            int idx = 2048 + t;
            __builtin_amdgcn_global_load_lds(
                (const AS1 unsigned int*)(src + (size_t)idx * 8),
                (AS3 unsigned int*)((char*)Al + (size_t)idx * 16), 16, 0, 0);
        }
        if (t < 96) arow_l[t] = arowg[(size_t)b * AROW_FLOATS + t];
    }

    // W fragments -> registers (L2-hot, reused across all 6 m-iters)
    bf16x8 whi_r[2][3], wlo_r[2][3];
    #pragma unroll
    for (int nt = 0; nt < 2; ++nt)
        #pragma unroll
        for (int ks = 0; ks < 3; ++ks) {
            int idx = (((w * 2 + nt) * 3 + ks) * 64 + lane) * 8;
            whi_r[nt][ks] = *(const bf16x8*)(Whi + idx);
            wlo_r[nt][ks] = *(const bf16x8*)(Wlo + idx);
        }

    __syncthreads();   // drains vmcnt -> LDS staging complete

    // ---- MFMA stage: wave w owns n-tiles {2w, 2w+1}; all operands LDS/registers ----
    {
        float sp[2] = {0.f, 0.f};

        #pragma unroll 1
        for (int m = 0; m < 6; ++m) {
            bf16x8 ahi[3], alo[3];
            #pragma unroll
            for (int ks = 0; ks < 3; ++ks) {
                const __bf16* p = Al + (size_t)(m * 3 + ks) * 1024 + lane * 8;
                ahi[ks] = *(const bf16x8*)p;
                alo[ks] = *(const bf16x8*)(p + 512);
            }
            float aj[4];
            #pragma unroll
            for (int ri = 0; ri < 4; ++ri)
                aj[ri] = arow_l[m * 16 + lkg * 4 + ri];

            f32x4 acc[2];
            acc[0] = (f32x4){0.f, 0.f, 0.f, 0.f};
            acc[1] = (f32x4){0.f, 0.f, 0.f, 0.f};
            #pragma unroll
            for (int ks = 0; ks < 3; ++ks) {
                #pragma unroll
                for (int nt = 0; nt < 2; ++nt) {
                    acc[nt] = __builtin_amdgcn_mfma_f32_16x16x32_bf16(ahi[ks], whi_r[nt][ks], acc[nt], 0, 0, 0);
                    acc[nt] = __builtin_amdgcn_mfma_f32_16x16x32_bf16(ahi[ks], wlo_r[nt][ks], acc[nt], 0, 0, 0);
                    acc[nt] = __builtin_amdgcn_mfma_f32_16x16x32_bf16(alo[ks], whi_r[nt][ks], acc[nt], 0, 0, 0);
                }
            }
            #pragma unroll
            for (int nt = 0; nt < 2; ++nt)
                #pragma unroll
                for (int ri = 0; ri < 4; ++ri)
                    sp[nt] = fmaf(aj[ri], fmaxf(acc[nt][ri], 0.f), sp[nt]);
        }

        #pragma unroll
        for (int nt = 0; nt < 2; ++nt) {
            float s = sp[nt];
            s += __shfl_xor(s, 16);
            s += __shfl_xor(s, 32);
            if (lane < 16) svec[(w * 2 + nt) * 16 + lrow] = s;
        }
    }
    __syncthreads();

    // ---- pooled[g] = sum_h W2[g,h] * s[h] ----
    if (t < H2) {
        const float* w2r = W2 + t * H1;
        float p0 = 0.f, p1 = 0.f, p2 = 0.f, p3 = 0.f;
        #pragma unroll 8
        for (int qq = 0; qq < H1 / 4; ++qq) {
            float4 sv = ((const float4*)svec)[qq];
            float4 wv4 = *(const float4*)&w2r[qq * 4];
            p0 = fmaf(sv.x, wv4.x, p0);
            p1 = fmaf(sv.y, wv4.y, p1);
            p2 = fmaf(sv.z, wv4.z, p2);
            p3 = fmaf(sv.w, wv4.w, p3);
        }
        pooled[t] = (p0 + p1) + (p2 + p3);
    }
    __syncthreads();

    // ---- fc1 = relu(Wo1 @ pooled + bo1) ----
    if (t < F1) {
        const float* wo1r = Wo1 + t * H2;
        float p0 = bo1[t], p1 = 0.f, p2 = 0.f, p3 = 0.f;
        #pragma unroll 8
        for (int qq = 0; qq < H2 / 4; ++qq) {
            float4 pv = ((const float4*)pooled)[qq];
            float4 wv4 = *(const float4*)&wo1r[qq * 4];
            p0 = fmaf(pv.x, wv4.x, p0);
            p1 = fmaf(pv.y, wv4.y, p1);
            p2 = fmaf(pv.z, wv4.z, p2);
            p3 = fmaf(pv.w, wv4.w, p3);
        }
        fc1[t] = fmaxf((p0 + p1) + (p2 + p3), 0.f);
    }
    __syncthreads();

    // ---- out = Wo2 @ fc1 + bo2 ----
    if (t < 64) {
        int o = t & 1;
        int f0 = t >> 1;
        const float* wo2r = Wo2 + o * F1;
        float p = 0.f;
        #pragma unroll
        for (int s = 0; s < 4; ++s)
            p = fmaf(wo2r[f0 + 32 * s], fc1[f0 + 32 * s], p);
        p += __shfl_xor(p, 2);
        p += __shfl_xor(p, 4);
        p += __shfl_xor(p, 8);
        p += __shfl_xor(p, 16);
        p += __shfl_xor(p, 32);
        if (t < 2) out[(size_t)b * 2 + t] = p + bo2[t];
    }
}

// ================= fallback: R9 monolithic kernel (ws too small) =================
__global__ __launch_bounds__(256)
void gcn_mono(const float* __restrict__ coh, const __bf16* __restrict__ Whi,
              const __bf16* __restrict__ Wlo, const int* __restrict__ ptab,
              const float* __restrict__ W2, const float* __restrict__ Wo1,
              const float* __restrict__ bo1, const float* __restrict__ Wo2,
              const float* __restrict__ bo2, float* __restrict__ out)
{
    __shared__ __align__(16) float A[JROWS * STR];
    __shared__ __align__(16) float svec_fc1[H1];
    __shared__ __align__(16) float pooled_dinv[H2];
    __shared__ __align__(16) float arow[96];
    float* dinv = pooled_dinv;
    float* pooled = pooled_dinv;
    const int b = blockIdx.x;
    const int t = threadIdx.x;
    const float* cb = coh + (size_t)b * NPAIR;

    for (int m = t; m < JROWS * 24; m += 256) {
        int i = m / 24, g = m - i * 24;
        *(float4*)&A[i * STR + g * 4] = make_float4(0.f, 0.f, 0.f, 0.f);
    }
    __syncthreads();
    for (int m = t; m < NPAIR; m += 256) {
        int p = ptab[m];
        int i = p >> 7, j = p & 127;
        float v = cb[m];
        A[i * STR + j] = v;
        A[j * STR + i] = v;
    }
    if (t < NN) {
        A[t * STR + t] = 1.0f;
        if (t < NREG) { A[NREG * STR + t] = 1.0f; A[t * STR + NREG] = 1.0f; }
    }
    __syncthreads();
    if (t < 256) dinv[t] = 0.0f;
    __syncthreads();
    if (t < NN) {
        const float4* row = (const float4*)&A[t * STR];
        float sx = 0.f, sy = 0.f, sz = 0.f, sw = 0.f;
        #pragma unroll
        for (int q = 0; q < 24; ++q) { float4 v = row[q]; sx += v.x; sy += v.y; sz += v.z; sw += v.w; }
        dinv[t] = 1.0f / sqrtf((sx + sy) + (sz + sw));
    }
    __syncthreads();
    for (int m = t; m < JROWS * 24; m += 256) {
        int i = m / 24;
        int c4 = (m - i * 24) * 4;
        float di = dinv[i];
        float4 dj = *(const float4*)&dinv[c4];
        float4 v = *(float4*)&A[i * STR + c4];
        v.x *= di * dj.x; v.y *= di * dj.y; v.z *= di * dj.z; v.w *= di * dj.w;
        *(float4*)&A[i * STR + c4] = v;
        if (i == NREG) *(float4*)&arow[c4] = v;
    }
    __syncthreads();
    for (int m = t; m < JROWS * 24; m += 256) {
        int i = m / 24;
        int c4 = (m - i * 24) * 4;
        float4 v = *(float4*)&A[i * STR + c4];
        uint4 p;
        p.x = pack_hl(v.x); p.y = pack_hl(v.y); p.z = pack_hl(v.z); p.w = pack_hl(v.w);
        *(uint4*)&A[i * STR + c4] = p;
    }
    __syncthreads();
    {
        const int w = t >> 6, lane = t & 63;
        const int lrow = lane & 15, lkg = lane >> 4;
        const unsigned int* Au = (const unsigned int*)A;
        bf16x8 whi_r[4][3], wlo_r[4][3];
        #pragma unroll
        for (int nt = 0; nt < 4; ++nt)
            #pragma unroll
            for (int ks = 0; ks < 3; ++ks) {
                int idx = (((w * 4 + nt) * 3 + ks) * 64 + lane) * 8;
                whi_r[nt][ks] = *(const bf16x8*)(Whi + idx);
                wlo_r[nt][ks] = *(const bf16x8*)(Wlo + idx);
            }
        float sp[4] = {0.f, 0.f, 0.f, 0.f};
        #pragma unroll 1
        for (int m = 0; m < 6; ++m) {
            bf16x8 ahi[3], alo[3];
            #pragma unroll
            for (int ks = 0; ks < 3; ++ks) {
                const uint4* src = (const uint4*)(Au + (m * 16 + lrow) * STR + ks * 32 + lkg * 8);
                uint4 a0 = src[0];
                uint4 a1 = src[1];
                u32x4v hw, lw;
                hw[0] = __builtin_amdgcn_perm(a0.y, a0.x, 0x05040100u);
                hw[1] = __builtin_amdgcn_perm(a0.w, a0.z, 0x05040100u);
                hw[2] = __builtin_amdgcn_perm(a1.y, a1.x, 0x05040100u);
                hw[3] = __builtin_amdgcn_perm(a1.w, a1.z, 0x05040100u);
                lw[0] = __builtin_amdgcn_perm(a0.y, a0.x, 0x07060302u);
                lw[1] = __builtin_amdgcn_perm(a0.w, a0.z, 0x07060302u);
                lw[2] = __builtin_amdgcn_perm(a1.y, a1.x, 0x07060302u);
                lw[3] = __builtin_amdgcn_perm(a1.w, a1.z, 0x07060302u);
                ahi[ks] = __builtin_bit_cast(bf16x8, hw);
                alo[ks] = __builtin_bit_cast(bf16x8, lw);
            }
            float aj[4];
            #pragma unroll
            for (int ri = 0; ri < 4; ++ri) aj[ri] = arow[m * 16 + lkg * 4 + ri];
            f32x4 acc[4];
            #pragma unroll
            for (int nt = 0; nt < 4; ++nt) acc[nt] = (f32x4){0.f, 0.f, 0.f, 0.f};
            #pragma unroll
            for (int ks = 0; ks < 3; ++ks)
                #pragma unroll
                for (int nt = 0; nt < 4; ++nt) {
                    acc[nt] = __builtin_amdgcn_mfma_f32_16x16x32_bf16(ahi[ks], whi_r[nt][ks], acc[nt], 0, 0, 0);
                    acc[nt] = __builtin_amdgcn_mfma_f32_16x16x32_bf16(ahi[ks], wlo_r[nt][ks], acc[nt], 0, 0, 0);
                    acc[nt] = __builtin_amdgcn_mfma_f32_16x16x32_bf16(alo[ks], whi_r[nt][ks], acc[nt], 0, 0, 0);
                }
            #pragma unroll
            for (int nt = 0; nt < 4; ++nt)
                #pragma unroll
                for (int ri = 0; ri < 4; ++ri)
                    sp[nt] = fmaf(aj[ri], fmaxf(acc[nt][ri], 0.f), sp[nt]);
        }
        __syncthreads();
        #pragma unroll
        for (int nt = 0; nt < 4; ++nt) {
            float s = sp[nt];
            s += __shfl_xor(s, 16);
            s += __shfl_xor(s, 32);
            if (lane < 16) svec_fc1[(w * 4 + nt) * 16 + lrow] = s;
        }
    }
    __syncthreads();
    {
        const float* w2r = W2 + t * H1;
        float p0 = 0.f, p1 = 0.f, p2 = 0.f, p3 = 0.f;
        #pragma unroll 8
        for (int qq = 0; qq < H1 / 4; ++qq) {
            float4 sv = ((const float4*)svec_fc1)[qq];
            float4 wv4 = *(const float4*)&w2r[qq * 4];
            p0 = fmaf(sv.x, wv4.x, p0); p1 = fmaf(sv.y, wv4.y, p1);
            p2 = fmaf(sv.z, wv4.z, p2); p3 = fmaf(sv.w, wv4.w, p3);
        }
        float pr = (p0 + p1) + (p2 + p3);
        __syncthreads();
        pooled[t] = pr;
    }
    __syncthreads();
    {
        float fr = 0.f;
        if (t < F1) {
            const float* wo1r = Wo1 + t * H2;
            float p0 = bo1[t], p1 = 0.f, p2 = 0.f, p3 = 0.f;
            #pragma unroll 8
            for (int qq = 0; qq < H2 / 4; ++qq) {
                float4 pv = ((const float4*)pooled)[qq];
                float4 wv4 = *(const float4*)&wo1r[qq * 4];
                p0 = fmaf(pv.x, wv4.x, p0); p1 = fmaf(pv.y, wv4.y, p1);
                p2 = fmaf(pv.z, wv4.z, p2); p3 = fmaf(pv.w, wv4.w, p3);
            }
            fr = fmaxf((p0 + p1) + (p2 + p3), 0.f);
        }
        __syncthreads();
        if (t < F1) svec_fc1[t] = fr;
    }
    __syncthreads();
    if (t < 64) {
        int o = t & 1;
        int f0 = t >> 1;
        const float* wo2r = Wo2 + o * F1;
        float p = 0.f;
        #pragma unroll
        for (int s = 0; s < 4; ++s) p = fmaf(wo2r[f0 + 32 * s], svec_fc1[f0 + 32 * s], p);
        p += __shfl_xor(p, 2); p += __shfl_xor(p, 4); p += __shfl_xor(p, 8);
        p += __shfl_xor(p, 16); p += __shfl_xor(p, 32);
        if (t < 2) out[(size_t)b * 2 + t] = p + bo2[t];
    }
}

extern "C" void kernel_launch(void* const* d_in, const int* in_sizes, int n_in,
                              void* d_out, int out_size, void* d_ws, size_t ws_size,
                              hipStream_t stream) {
    const float* coh = (const float*)d_in[0];
    const float* W1  = (const float*)d_in[1];
    const float* W2  = (const float*)d_in[2];
    const float* Wo1 = (const float*)d_in[3];
    const float* bo1 = (const float*)d_in[4];
    const float* Wo2 = (const float*)d_in[5];
    const float* bo2 = (const float*)d_in[6];
    float* outp = (float*)d_out;

    __bf16* Whi = (__bf16*)d_ws;                        // 49152 B
    __bf16* Wlo = Whi + 24576;                          // 49152 B
    int*    ptab = (int*)((char*)d_ws + 98304);         // 16020 B -> header ends 114688

    const int B = in_sizes[0] / NPAIR;
    prep<<<96, 256, 0, stream>>>(W1, Whi, Wlo, ptab);

    const size_t header = 114688;
    const size_t per_graph = (size_t)FRAG_ELEMS_PG * 2 + AROW_FLOATS * 4;   // 36864+384
    long cap = (ws_size > header) ? (long)((ws_size - header) / per_graph) : 0;
    if (cap > B) cap = B;

    if (cap >= 512) {
        __bf16* Afrag = (__bf16*)((char*)d_ws + header);
        float*  arowg = (float*)((char*)d_ws + header + (size_t)cap * FRAG_ELEMS_PG * 2);
        for (int off = 0; off < B; off += (int)cap) {
            int n = B - off;
            if (n > cap) n = (int)cap;
            k1_build<<<n, 256, 0, stream>>>(coh + (size_t)off * NPAIR, ptab, Afrag, arowg);
            k2_gemm<<<n, 512, 0, stream>>>(Afrag, arowg, Whi, Wlo, W2, Wo1, bo1, Wo2, bo2,
                                           outp + (size_t)off * 2);
        }
    } else {
        gcn_mono<<<B, 256, 0, stream>>>(coh, Whi, Wlo, ptab, W2, Wo1, bo1, Wo2, bo2, outp);
    }
}

// Round 13
// 169.209 us; speedup vs baseline: 1.6325x; 1.4410x over previous
//
#include <hip/hip_runtime.h>
#include <hip/hip_bf16.h>
#include <math.h>

#define NREG 90
#define NN 91
#define JROWS 96
#define STR 100           // fp32 A LDS stride (words)
#define NPAIR 4005
#define H1 256
#define H2 256
#define F1 128

#define FRAG_ELEMS_PG 18432      // 18 groups x (512 hi + 512 lo) bf16 = 36864 B
#define AROW_FLOATS 96

typedef __bf16 bf16x8 __attribute__((ext_vector_type(8)));
typedef float  f32x4  __attribute__((ext_vector_type(4)));
typedef unsigned int u32x4v __attribute__((ext_vector_type(4)));

#define AS1 __attribute__((address_space(1)))
#define AS3 __attribute__((address_space(3)))

__device__ __forceinline__ unsigned int pack_hl(float f) {
    __bf16 h = (__bf16)f;
    __bf16 l = (__bf16)(f - (float)h);
    unsigned short hb = __builtin_bit_cast(unsigned short, h);
    unsigned short lb = __builtin_bit_cast(unsigned short, l);
    return ((unsigned int)lb << 16) | (unsigned int)hb;
}

// ---- one-shot prep: W1 frags + pair table + transposed tail weights ----
__global__ void prep(const float* __restrict__ W1, const float* __restrict__ W2,
                     const float* __restrict__ Wo1,
                     __bf16* __restrict__ Whi, __bf16* __restrict__ Wlo,
                     int* __restrict__ ptab,
                     float* __restrict__ W2T, float* __restrict__ Wo1T) {
    int t = blockIdx.x * 256 + threadIdx.x;       // 0..65535
    if (t < 24576) {
        int e  = t & 7;
        int ln = (t >> 3) & 63;
        int g  = t >> 9;
        int nt = g / 3;
        int ks = g - nt * 3;
        int h = nt * 16 + (ln & 15);
        int k = ks * 32 + (ln >> 4) * 8 + e;
        float v = (k < NN) ? W1[h * NN + k] : 0.0f;
        __bf16 hb = (__bf16)v;
        __bf16 lb = (__bf16)(v - (float)hb);
        Whi[t] = hb;
        Wlo[t] = lb;
    }
    if (t < 65536)                                  // W2T[h][g] = W2[g][h]
        W2T[t] = W2[(t & 255) * 256 + (t >> 8)];
    if (t < 32768)                                  // Wo1T[h][f] = Wo1[f][h]
        Wo1T[t] = Wo1[(t & 127) * 256 + (t >> 7)];
    if (t < NPAIR) {
        float disc = 32041.0f - 8.0f * (float)t;
        int i = (int)floorf((179.0f - sqrtf(disc)) * 0.5f);
        if (i < 0) i = 0;
        while (i > 0 && t < i * (179 - i) / 2) --i;
        while (t >= (i + 1) * (178 - i) / 2) ++i;
        int j = i + 1 + (t - i * (179 - i) / 2);
        ptab[t] = (i << 7) | j;
    }
}

// ================= kernel 1: build A_hat, emit MFMA-ready fragments =================
__global__ __launch_bounds__(256)
void k1_build(const float* __restrict__ coh,     // [n, 4005] (chunk-offset)
              const int*   __restrict__ ptab,
              __bf16*      __restrict__ Afrag,   // [n][18432]
              float*       __restrict__ arowg)   // [n][96]
{
    __shared__ __align__(16) float A[JROWS * STR];
    __shared__ __align__(16) float dinv[128];

    const int b = blockIdx.x;
    const int t = threadIdx.x;
    const float* cb = coh + (size_t)b * NPAIR;

    for (int m = t; m < JROWS * (STR / 4); m += 256)
        ((float4*)A)[m] = make_float4(0.f, 0.f, 0.f, 0.f);
    if (t < 128) dinv[t] = 0.0f;
    __syncthreads();

    for (int m = t; m < NPAIR; m += 256) {
        int p = ptab[m];
        int i = p >> 7, j = p & 127;
        float v = cb[m];
        A[i * STR + j] = v;
        A[j * STR + i] = v;
    }
    if (t < NN) {
        A[t * STR + t] = 1.0f;
        if (t < NREG) {
            A[NREG * STR + t] = 1.0f;
            A[t * STR + NREG] = 1.0f;
        }
    }
    __syncthreads();

    if (t < NN) {
        const float4* row = (const float4*)&A[t * STR];
        float sx = 0.f, sy = 0.f, sz = 0.f, sw = 0.f;
        #pragma unroll
        for (int q = 0; q < STR / 4; ++q) {
            float4 v = row[q];
            sx += v.x; sy += v.y; sz += v.z; sw += v.w;
        }
        dinv[t] = 1.0f / sqrtf((sx + sy) + (sz + sw));
    }
    __syncthreads();

    {
        const int w = t >> 6, lane = t & 63;
        const int lrow = lane & 15, lkg = lane >> 4;
        __bf16* frag_g = Afrag + (size_t)b * FRAG_ELEMS_PG;

        for (int g = w; g < 18; g += 4) {
            int m = g / 3, ks = g - m * 3;
            int row = m * 16 + lrow;
            int cb2 = ks * 32 + lkg * 8;
            float dr = dinv[row];
            float4 f0 = *(const float4*)&A[row * STR + cb2];
            float4 f1 = *(const float4*)&A[row * STR + cb2 + 4];
            float4 d0 = *(const float4*)&dinv[cb2];
            float4 d1 = *(const float4*)&dinv[cb2 + 4];
            float v0 = f0.x * dr * d0.x, v1 = f0.y * dr * d0.y;
            float v2 = f0.z * dr * d0.z, v3 = f0.w * dr * d0.w;
            float v4 = f1.x * dr * d1.x, v5 = f1.y * dr * d1.y;
            float v6 = f1.z * dr * d1.z, v7 = f1.w * dr * d1.w;
            bf16x8 hh, ll;
            hh[0] = (__bf16)v0; ll[0] = (__bf16)(v0 - (float)hh[0]);
            hh[1] = (__bf16)v1; ll[1] = (__bf16)(v1 - (float)hh[1]);
            hh[2] = (__bf16)v2; ll[2] = (__bf16)(v2 - (float)hh[2]);
            hh[3] = (__bf16)v3; ll[3] = (__bf16)(v3 - (float)hh[3]);
            hh[4] = (__bf16)v4; ll[4] = (__bf16)(v4 - (float)hh[4]);
            hh[5] = (__bf16)v5; ll[5] = (__bf16)(v5 - (float)hh[5]);
            hh[6] = (__bf16)v6; ll[6] = (__bf16)(v6 - (float)hh[6]);
            hh[7] = (__bf16)v7; ll[7] = (__bf16)(v7 - (float)hh[7]);
            *(bf16x8*)(frag_g + (size_t)g * 1024 + lane * 8)       = hh;
            *(bf16x8*)(frag_g + (size_t)g * 1024 + 512 + lane * 8) = ll;
        }
        if (t < 24) {
            int c4 = t * 4;
            float4 f = *(const float4*)&A[NREG * STR + c4];
            float4 d = *(const float4*)&dinv[c4];
            float dr = dinv[NREG];
            float4 o;
            o.x = f.x * dr * d.x; o.y = f.y * dr * d.y;
            o.z = f.z * dr * d.z; o.w = f.w * dr * d.w;
            *(float4*)&arowg[(size_t)b * AROW_FLOATS + c4] = o;
        }
    }
}

// ================= kernel 2: LDS-staged MFMA z-stage -> svec =================
__global__ __launch_bounds__(512)
void k2_gemm(const __bf16* __restrict__ Afrag,   // [n][18432]
             const float*  __restrict__ arowg,   // [n][96]
             const __bf16* __restrict__ Whi,
             const __bf16* __restrict__ Wlo,
             float*        __restrict__ svec_out) // [n][256] (chunk-offset)
{
    __shared__ __align__(16) __bf16 Al[FRAG_ELEMS_PG];  // 36864 B
    __shared__ __align__(16) float arow_l[96];

    const int b = blockIdx.x;
    const int t = threadIdx.x;
    const int w = t >> 6, lane = t & 63;
    const int lrow = lane & 15, lkg = lane >> 4;

    {
        const __bf16* src = Afrag + (size_t)b * FRAG_ELEMS_PG;
        #pragma unroll
        for (int k = 0; k < 4; ++k) {
            int idx = k * 512 + t;
            __builtin_amdgcn_global_load_lds(
                (const AS1 unsigned int*)(src + (size_t)idx * 8),
                (AS3 unsigned int*)((char*)Al + (size_t)idx * 16), 16, 0, 0);
        }
        if (t < 256) {
            int idx = 2048 + t;
            __builtin_amdgcn_global_load_lds(
                (const AS1 unsigned int*)(src + (size_t)idx * 8),
                (AS3 unsigned int*)((char*)Al + (size_t)idx * 16), 16, 0, 0);
        }
        if (t < 96) arow_l[t] = arowg[(size_t)b * AROW_FLOATS + t];
    }

    bf16x8 whi_r[2][3], wlo_r[2][3];
    #pragma unroll
    for (int nt = 0; nt < 2; ++nt)
        #pragma unroll
        for (int ks = 0; ks < 3; ++ks) {
            int idx = (((w * 2 + nt) * 3 + ks) * 64 + lane) * 8;
            whi_r[nt][ks] = *(const bf16x8*)(Whi + idx);
            wlo_r[nt][ks] = *(const bf16x8*)(Wlo + idx);
        }

    __syncthreads();   // staging complete

    float sp[2] = {0.f, 0.f};

    #pragma unroll 1
    for (int m = 0; m < 6; ++m) {
        bf16x8 ahi[3], alo[3];
        #pragma unroll
        for (int ks = 0; ks < 3; ++ks) {
            const __bf16* p = Al + (size_t)(m * 3 + ks) * 1024 + lane * 8;
            ahi[ks] = *(const bf16x8*)p;
            alo[ks] = *(const bf16x8*)(p + 512);
        }
        float aj[4];
        #pragma unroll
        for (int ri = 0; ri < 4; ++ri)
            aj[ri] = arow_l[m * 16 + lkg * 4 + ri];

        f32x4 acc[2];
        acc[0] = (f32x4){0.f, 0.f, 0.f, 0.f};
        acc[1] = (f32x4){0.f, 0.f, 0.f, 0.f};
        #pragma unroll
        for (int ks = 0; ks < 3; ++ks) {
            #pragma unroll
            for (int nt = 0; nt < 2; ++nt) {
                acc[nt] = __builtin_amdgcn_mfma_f32_16x16x32_bf16(ahi[ks], whi_r[nt][ks], acc[nt], 0, 0, 0);
                acc[nt] = __builtin_amdgcn_mfma_f32_16x16x32_bf16(ahi[ks], wlo_r[nt][ks], acc[nt], 0, 0, 0);
                acc[nt] = __builtin_amdgcn_mfma_f32_16x16x32_bf16(alo[ks], whi_r[nt][ks], acc[nt], 0, 0, 0);
            }
        }
        #pragma unroll
        for (int nt = 0; nt < 2; ++nt)
            #pragma unroll
            for (int ri = 0; ri < 4; ++ri)
                sp[nt] = fmaf(aj[ri], fmaxf(acc[nt][ri], 0.f), sp[nt]);
    }

    #pragma unroll
    for (int nt = 0; nt < 2; ++nt) {
        float s = sp[nt];
        s += __shfl_xor(s, 16);
        s += __shfl_xor(s, 32);
        if (lane < 16) svec_out[(size_t)b * 256 + (w * 2 + nt) * 16 + lrow] = s;
    }
}

// ================= kernel 3: batched fp32 MLP tail (coalesced weights) =================
__global__ __launch_bounds__(512)
void k3_tail(const float* __restrict__ svec,   // [B][256]
             const float* __restrict__ W2T,    // [256][256]
             const float* __restrict__ Wo1T,   // [256][128]
             const float* __restrict__ bo1,
             const float* __restrict__ Wo2,    // [2][128]
             const float* __restrict__ bo2,
             float* __restrict__ out, int B)
{
    __shared__ __align__(16) float Sl[32][260];   // S-tile, then reused as fc1 buffer
    __shared__ __align__(16) float Pl[32][260];   // pooled (256 channels! was the R12 bug)

    const int t = threadIdx.x;
    const int b0 = blockIdx.x * 32;

    for (int idx = t; idx < 2048; idx += 512) {
        int row = idx >> 6, c4 = (idx & 63) << 2;
        float4 v = make_float4(0.f, 0.f, 0.f, 0.f);
        if (b0 + row < B) v = *(const float4*)&svec[(size_t)(b0 + row) * 256 + c4];
        *(float4*)&Sl[row][c4] = v;
    }
    __syncthreads();

    // ---- pooled[b][g] = sum_h S[b][h] * W2T[h][g]; thread: 4 b x 4 g ----
    {
        const int bq = t >> 6, gq = t & 63;     // bq wave-uniform -> S reads broadcast
        float acc[4][4];
        #pragma unroll
        for (int i = 0; i < 4; ++i)
            #pragma unroll
            for (int j = 0; j < 4; ++j) acc[i][j] = 0.f;
        #pragma unroll 2
        for (int h = 0; h < 256; ++h) {
            float4 wv = *(const float4*)&W2T[h * 256 + gq * 4];   // coalesced
            float s0 = Sl[bq * 4 + 0][h];
            float s1 = Sl[bq * 4 + 1][h];
            float s2 = Sl[bq * 4 + 2][h];
            float s3 = Sl[bq * 4 + 3][h];
            acc[0][0] = fmaf(s0, wv.x, acc[0][0]); acc[0][1] = fmaf(s0, wv.y, acc[0][1]);
            acc[0][2] = fmaf(s0, wv.z, acc[0][2]); acc[0][3] = fmaf(s0, wv.w, acc[0][3]);
            acc[1][0] = fmaf(s1, wv.x, acc[1][0]); acc[1][1] = fmaf(s1, wv.y, acc[1][1]);
            acc[1][2] = fmaf(s1, wv.z, acc[1][2]); acc[1][3] = fmaf(s1, wv.w, acc[1][3]);
            acc[2][0] = fmaf(s2, wv.x, acc[2][0]); acc[2][1] = fmaf(s2, wv.y, acc[2][1]);
            acc[2][2] = fmaf(s2, wv.z, acc[2][2]); acc[2][3] = fmaf(s2, wv.w, acc[2][3]);
            acc[3][0] = fmaf(s3, wv.x, acc[3][0]); acc[3][1] = fmaf(s3, wv.y, acc[3][1]);
            acc[3][2] = fmaf(s3, wv.z, acc[3][2]); acc[3][3] = fmaf(s3, wv.w, acc[3][3]);
        }
        #pragma unroll
        for (int i = 0; i < 4; ++i)
            #pragma unroll
            for (int j = 0; j < 4; ++j)
                Pl[bq * 4 + i][gq * 4 + j] = acc[i][j];
    }
    __syncthreads();

    // ---- fc1[b][f] = relu(sum_h P[b][h] * Wo1T[h][f] + bo1[f]); thread: 4 b x 2 f ----
    float* Fl = &Sl[0][0];                       // reuse S buffer, stride 132
    {
        const int bq = t >> 6, fq = t & 63;
        float acc[4][2];
        #pragma unroll
        for (int i = 0; i < 4; ++i) { acc[i][0] = 0.f; acc[i][1] = 0.f; }
        #pragma unroll 2
        for (int h = 0; h < 256; ++h) {
            float2 wv = *(const float2*)&Wo1T[h * 128 + fq * 2];  // coalesced
            float s0 = Pl[bq * 4 + 0][h];
            float s1 = Pl[bq * 4 + 1][h];
            float s2 = Pl[bq * 4 + 2][h];
            float s3 = Pl[bq * 4 + 3][h];
            acc[0][0] = fmaf(s0, wv.x, acc[0][0]); acc[0][1] = fmaf(s0, wv.y, acc[0][1]);
            acc[1][0] = fmaf(s1, wv.x, acc[1][0]); acc[1][1] = fmaf(s1, wv.y, acc[1][1]);
            acc[2][0] = fmaf(s2, wv.x, acc[2][0]); acc[2][1] = fmaf(s2, wv.y, acc[2][1]);
            acc[3][0] = fmaf(s3, wv.x, acc[3][0]); acc[3][1] = fmaf(s3, wv.y, acc[3][1]);
        }
        float b0f = bo1[fq * 2 + 0];
        float b1f = bo1[fq * 2 + 1];
        __syncthreads();   // Sl reads done before overwrite as Fl
        #pragma unroll
        for (int i = 0; i < 4; ++i) {
            Fl[(bq * 4 + i) * 132 + fq * 2 + 0] = fmaxf(acc[i][0] + b0f, 0.f);
            Fl[(bq * 4 + i) * 132 + fq * 2 + 1] = fmaxf(acc[i][1] + b1f, 0.f);
        }
    }
    __syncthreads();

    // ---- out[b][o] = Wo2[o] . fc1[b] + bo2[o] ----
    if (t < 256) {
        int b = t >> 3, o = (t >> 2) & 1, q = t & 3;
        const float* wo = Wo2 + o * F1 + q * 32;
        const float* fv = Fl + b * 132 + q * 32;
        float p = 0.f;
        #pragma unroll
        for (int k = 0; k < 32; ++k) p = fmaf(wo[k], fv[k], p);
        p += __shfl_xor(p, 1);
        p += __shfl_xor(p, 2);
        if (q == 0 && b0 + b < B) out[(size_t)(b0 + b) * 2 + o] = p + bo2[o];
    }
}

// ================= fallback: R9 monolithic kernel (ws too small) =================
__global__ __launch_bounds__(256)
void gcn_mono(const float* __restrict__ coh, const __bf16* __restrict__ Whi,
              const __bf16* __restrict__ Wlo, const int* __restrict__ ptab,
              const float* __restrict__ W2, const float* __restrict__ Wo1,
              const float* __restrict__ bo1, const float* __restrict__ Wo2,
              const float* __restrict__ bo2, float* __restrict__ out)
{
    __shared__ __align__(16) float A[JROWS * STR];
    __shared__ __align__(16) float svec_fc1[H1];
    __shared__ __align__(16) float pooled_dinv[H2];
    __shared__ __align__(16) float arow[96];
    float* dinv = pooled_dinv;
    float* pooled = pooled_dinv;
    const int b = blockIdx.x;
    const int t = threadIdx.x;
    const float* cb = coh + (size_t)b * NPAIR;

    for (int m = t; m < JROWS * 24; m += 256) {
        int i = m / 24, g = m - i * 24;
        *(float4*)&A[i * STR + g * 4] = make_float4(0.f, 0.f, 0.f, 0.f);
    }
    __syncthreads();
    for (int m = t; m < NPAIR; m += 256) {
        int p = ptab[m];
        int i = p >> 7, j = p & 127;
        float v = cb[m];
        A[i * STR + j] = v;
        A[j * STR + i] = v;
    }
    if (t < NN) {
        A[t * STR + t] = 1.0f;
        if (t < NREG) { A[NREG * STR + t] = 1.0f; A[t * STR + NREG] = 1.0f; }
    }
    __syncthreads();
    if (t < 256) dinv[t] = 0.0f;
    __syncthreads();
    if (t < NN) {
        const float4* row = (const float4*)&A[t * STR];
        float sx = 0.f, sy = 0.f, sz = 0.f, sw = 0.f;
        #pragma unroll
        for (int q = 0; q < 24; ++q) { float4 v = row[q]; sx += v.x; sy += v.y; sz += v.z; sw += v.w; }
        dinv[t] = 1.0f / sqrtf((sx + sy) + (sz + sw));
    }
    __syncthreads();
    for (int m = t; m < JROWS * 24; m += 256) {
        int i = m / 24;
        int c4 = (m - i * 24) * 4;
        float di = dinv[i];
        float4 dj = *(const float4*)&dinv[c4];
        float4 v = *(float4*)&A[i * STR + c4];
        v.x *= di * dj.x; v.y *= di * dj.y; v.z *= di * dj.z; v.w *= di * dj.w;
        *(float4*)&A[i * STR + c4] = v;
        if (i == NREG) *(float4*)&arow[c4] = v;
    }
    __syncthreads();
    for (int m = t; m < JROWS * 24; m += 256) {
        int i = m / 24;
        int c4 = (m - i * 24) * 4;
        float4 v = *(float4*)&A[i * STR + c4];
        uint4 p;
        p.x = pack_hl(v.x); p.y = pack_hl(v.y); p.z = pack_hl(v.z); p.w = pack_hl(v.w);
        *(uint4*)&A[i * STR + c4] = p;
    }
    __syncthreads();
    {
        const int w = t >> 6, lane = t & 63;
        const int lrow = lane & 15, lkg = lane >> 4;
        const unsigned int* Au = (const unsigned int*)A;
        bf16x8 whi_r[4][3], wlo_r[4][3];
        #pragma unroll
        for (int nt = 0; nt < 4; ++nt)
            #pragma unroll
            for (int ks = 0; ks < 3; ++ks) {
                int idx = (((w * 4 + nt) * 3 + ks) * 64 + lane) * 8;
                whi_r[nt][ks] = *(const bf16x8*)(Whi + idx);
                wlo_r[nt][ks] = *(const bf16x8*)(Wlo + idx);
            }
        float sp[4] = {0.f, 0.f, 0.f, 0.f};
        #pragma unroll 1
        for (int m = 0; m < 6; ++m) {
            bf16x8 ahi[3], alo[3];
            #pragma unroll
            for (int ks = 0; ks < 3; ++ks) {
                const uint4* src = (const uint4*)(Au + (m * 16 + lrow) * STR + ks * 32 + lkg * 8);
                uint4 a0 = src[0];
                uint4 a1 = src[1];
                u32x4v hw, lw;
                hw[0] = __builtin_amdgcn_perm(a0.y, a0.x, 0x05040100u);
                hw[1] = __builtin_amdgcn_perm(a0.w, a0.z, 0x05040100u);
                hw[2] = __builtin_amdgcn_perm(a1.y, a1.x, 0x05040100u);
                hw[3] = __builtin_amdgcn_perm(a1.w, a1.z, 0x05040100u);
                lw[0] = __builtin_amdgcn_perm(a0.y, a0.x, 0x07060302u);
                lw[1] = __builtin_amdgcn_perm(a0.w, a0.z, 0x07060302u);
                lw[2] = __builtin_amdgcn_perm(a1.y, a1.x, 0x07060302u);
                lw[3] = __builtin_amdgcn_perm(a1.w, a1.z, 0x07060302u);
                ahi[ks] = __builtin_bit_cast(bf16x8, hw);
                alo[ks] = __builtin_bit_cast(bf16x8, lw);
            }
            float aj[4];
            #pragma unroll
            for (int ri = 0; ri < 4; ++ri) aj[ri] = arow[m * 16 + lkg * 4 + ri];
            f32x4 acc[4];
            #pragma unroll
            for (int nt = 0; nt < 4; ++nt) acc[nt] = (f32x4){0.f, 0.f, 0.f, 0.f};
            #pragma unroll
            for (int ks = 0; ks < 3; ++ks)
                #pragma unroll
                for (int nt = 0; nt < 4; ++nt) {
                    acc[nt] = __builtin_amdgcn_mfma_f32_16x16x32_bf16(ahi[ks], whi_r[nt][ks], acc[nt], 0, 0, 0);
                    acc[nt] = __builtin_amdgcn_mfma_f32_16x16x32_bf16(ahi[ks], wlo_r[nt][ks], acc[nt], 0, 0, 0);
                    acc[nt] = __builtin_amdgcn_mfma_f32_16x16x32_bf16(alo[ks], whi_r[nt][ks], acc[nt], 0, 0, 0);
                }
            #pragma unroll
            for (int nt = 0; nt < 4; ++nt)
                #pragma unroll
                for (int ri = 0; ri < 4; ++ri)
                    sp[nt] = fmaf(aj[ri], fmaxf(acc[nt][ri], 0.f), sp[nt]);
        }
        __syncthreads();
        #pragma unroll
        for (int nt = 0; nt < 4; ++nt) {
            float s = sp[nt];
            s += __shfl_xor(s, 16);
            s += __shfl_xor(s, 32);
            if (lane < 16) svec_fc1[(w * 4 + nt) * 16 + lrow] = s;
        }
    }
    __syncthreads();
    {
        const float* w2r = W2 + t * H1;
        float p0 = 0.f, p1 = 0.f, p2 = 0.f, p3 = 0.f;
        #pragma unroll 8
        for (int qq = 0; qq < H1 / 4; ++qq) {
            float4 sv = ((const float4*)svec_fc1)[qq];
            float4 wv4 = *(const float4*)&w2r[qq * 4];
            p0 = fmaf(sv.x, wv4.x, p0); p1 = fmaf(sv.y, wv4.y, p1);
            p2 = fmaf(sv.z, wv4.z, p2); p3 = fmaf(sv.w, wv4.w, p3);
        }
        float pr = (p0 + p1) + (p2 + p3);
        __syncthreads();
        pooled[t] = pr;
    }
    __syncthreads();
    {
        float fr = 0.f;
        if (t < F1) {
            const float* wo1r = Wo1 + t * H2;
            float p0 = bo1[t], p1 = 0.f, p2 = 0.f, p3 = 0.f;
            #pragma unroll 8
            for (int qq = 0; qq < H2 / 4; ++qq) {
                float4 pv = ((const float4*)pooled)[qq];
                float4 wv4 = *(const float4*)&wo1r[qq * 4];
                p0 = fmaf(pv.x, wv4.x, p0); p1 = fmaf(pv.y, wv4.y, p1);
                p2 = fmaf(pv.z, wv4.z, p2); p3 = fmaf(pv.w, wv4.w, p3);
            }
            fr = fmaxf((p0 + p1) + (p2 + p3), 0.f);
        }
        __syncthreads();
        if (t < F1) svec_fc1[t] = fr;
    }
    __syncthreads();
    if (t < 64) {
        int o = t & 1;
        int f0 = t >> 1;
        const float* wo2r = Wo2 + o * F1;
        float p = 0.f;
        #pragma unroll
        for (int s = 0; s < 4; ++s) p = fmaf(wo2r[f0 + 32 * s], svec_fc1[f0 + 32 * s], p);
        p += __shfl_xor(p, 2); p += __shfl_xor(p, 4); p += __shfl_xor(p, 8);
        p += __shfl_xor(p, 16); p += __shfl_xor(p, 32);
        if (t < 2) out[(size_t)b * 2 + t] = p + bo2[t];
    }
}

extern "C" void kernel_launch(void* const* d_in, const int* in_sizes, int n_in,
                              void* d_out, int out_size, void* d_ws, size_t ws_size,
                              hipStream_t stream) {
    const float* coh = (const float*)d_in[0];
    const float* W1  = (const float*)d_in[1];
    const float* W2  = (const float*)d_in[2];
    const float* Wo1 = (const float*)d_in[3];
    const float* bo1 = (const float*)d_in[4];
    const float* Wo2 = (const float*)d_in[5];
    const float* bo2 = (const float*)d_in[6];
    float* outp = (float*)d_out;

    const int B = in_sizes[0] / NPAIR;            // 4096

    // ws layout
    __bf16* Whi  = (__bf16*)d_ws;                               // 49152 B
    __bf16* Wlo  = Whi + 24576;                                 // 49152 B
    int*    ptab = (int*)((char*)d_ws + 98304);                 // -> pad to 114688
    float*  W2T  = (float*)((char*)d_ws + 114688);              // 262144 B
    float*  Wo1T = (float*)((char*)d_ws + 376832);              // 131072 B
    float*  svecw= (float*)((char*)d_ws + 507904);              // B*1024 B
    const size_t header = 507904 + (size_t)B * 1024;

    prep<<<256, 256, 0, stream>>>(W1, W2, Wo1, Whi, Wlo, ptab, W2T, Wo1T);

    const size_t per_graph = (size_t)FRAG_ELEMS_PG * 2 + AROW_FLOATS * 4;   // 37248
    long cap = (ws_size > header) ? (long)((ws_size - header) / per_graph) : 0;
    if (cap > B) cap = B;

    if (cap >= 512) {
        __bf16* Afrag = (__bf16*)((char*)d_ws + header);
        float*  arowg = (float*)((char*)d_ws + header + (size_t)cap * FRAG_ELEMS_PG * 2);
        for (int off = 0; off < B; off += (int)cap) {
            int n = B - off;
            if (n > cap) n = (int)cap;
            k1_build<<<n, 256, 0, stream>>>(coh + (size_t)off * NPAIR, ptab, Afrag, arowg);
            k2_gemm<<<n, 512, 0, stream>>>(Afrag, arowg, Whi, Wlo,
                                           svecw + (size_t)off * 256);
        }
        k3_tail<<<(B + 31) / 32, 512, 0, stream>>>(svecw, W2T, Wo1T, bo1, Wo2, bo2, outp, B);
    } else {
        gcn_mono<<<B, 256, 0, stream>>>(coh, Whi, Wlo, ptab, W2, Wo1, bo1, Wo2, bo2, outp);
    }
}

// Round 14
// 167.497 us; speedup vs baseline: 1.6492x; 1.0102x over previous
//
#include <hip/hip_runtime.h>
#include <hip/hip_bf16.h>
#include <math.h>

#define NREG 90
#define NN 91
#define JROWS 96
#define STR 100           // fp32 A LDS stride (words)
#define NPAIR 4005
#define H1 256
#define H2 256
#define F1 128

typedef __bf16 bf16x8 __attribute__((ext_vector_type(8)));
typedef float  f32x4  __attribute__((ext_vector_type(4)));
typedef unsigned int u32x4v __attribute__((ext_vector_type(4)));

__device__ __forceinline__ unsigned int pack_hl(float f) {
    __bf16 h = (__bf16)f;
    __bf16 l = (__bf16)(f - (float)h);
    unsigned short hb = __builtin_bit_cast(unsigned short, h);
    unsigned short lb = __builtin_bit_cast(unsigned short, l);
    return ((unsigned int)lb << 16) | (unsigned int)hb;
}

// ---- one-shot prep: W1 frags + pair table + transposed tail weights ----
__global__ void prep(const float* __restrict__ W1, const float* __restrict__ W2,
                     const float* __restrict__ Wo1,
                     __bf16* __restrict__ Whi, __bf16* __restrict__ Wlo,
                     int* __restrict__ ptab,
                     float* __restrict__ W2T, float* __restrict__ Wo1T) {
    int t = blockIdx.x * 256 + threadIdx.x;       // 0..65535
    if (t < 24576) {
        int e  = t & 7;
        int ln = (t >> 3) & 63;
        int g  = t >> 9;
        int nt = g / 3;
        int ks = g - nt * 3;
        int h = nt * 16 + (ln & 15);
        int k = ks * 32 + (ln >> 4) * 8 + e;
        float v = (k < NN) ? W1[h * NN + k] : 0.0f;
        __bf16 hb = (__bf16)v;
        __bf16 lb = (__bf16)(v - (float)hb);
        Whi[t] = hb;
        Wlo[t] = lb;
    }
    if (t < 65536)                                  // W2T[h][g] = W2[g][h]
        W2T[t] = W2[(t & 255) * 256 + (t >> 8)];
    if (t < 32768)                                  // Wo1T[h][f] = Wo1[f][h]
        Wo1T[t] = Wo1[(t & 127) * 256 + (t >> 7)];
    if (t < NPAIR) {
        float disc = 32041.0f - 8.0f * (float)t;
        int i = (int)floorf((179.0f - sqrtf(disc)) * 0.5f);
        if (i < 0) i = 0;
        while (i > 0 && t < i * (179 - i) / 2) --i;
        while (t >= (i + 1) * (178 - i) / 2) ++i;
        int j = i + 1 + (t - i * (179 - i) / 2);
        ptab[t] = (i << 7) | j;
    }
}

// ========== merged kernel: build A_hat + pack + MFMA z-stage -> svec ==========
__global__ __launch_bounds__(256)
void mk_build_gemm(const float* __restrict__ coh,    // [B, 4005]
                   const int*   __restrict__ ptab,
                   const __bf16* __restrict__ Whi,   // [16][3][64][8]
                   const __bf16* __restrict__ Wlo,
                   float* __restrict__ svec_out)     // [B][256]
{
    __shared__ __align__(16) float A[JROWS * STR];   // 38400 B
    __shared__ __align__(16) float dinv[128];
    __shared__ __align__(16) float arow[96];
    // ~39.3 KB -> 4 blocks/CU

    const int b = blockIdx.x;
    const int t = threadIdx.x;
    const float* cb = coh + (size_t)b * NPAIR;

    // ---- 1) zero A ----
    for (int m = t; m < JROWS * (STR / 4); m += 256)
        ((float4*)A)[m] = make_float4(0.f, 0.f, 0.f, 0.f);
    if (t < 128) dinv[t] = 0.0f;
    __syncthreads();

    // ---- 2) scatter + supernode + identity ----
    for (int m = t; m < NPAIR; m += 256) {
        int p = ptab[m];
        int i = p >> 7, j = p & 127;
        float v = cb[m];
        A[i * STR + j] = v;
        A[j * STR + i] = v;
    }
    if (t < NN) {
        A[t * STR + t] = 1.0f;
        if (t < NREG) {
            A[NREG * STR + t] = 1.0f;
            A[t * STR + NREG] = 1.0f;
        }
    }
    __syncthreads();

    // ---- 3) degree^-1/2 ----
    if (t < NN) {
        const float4* row = (const float4*)&A[t * STR];
        float sx = 0.f, sy = 0.f, sz = 0.f, sw = 0.f;
        #pragma unroll
        for (int q = 0; q < STR / 4; ++q) {
            float4 v = row[q];
            sx += v.x; sy += v.y; sz += v.z; sw += v.w;
        }
        dinv[t] = 1.0f / sqrtf((sx + sy) + (sz + sw));
    }
    __syncthreads();

    // ---- 4) A_hat = dinv_i * A * dinv_j; save fp32 row 90 ----
    for (int m = t; m < JROWS * (STR / 4); m += 256) {
        int i = m / (STR / 4);
        int c4 = (m - i * (STR / 4)) * 4;
        float di = dinv[i];
        float4 dj = *(const float4*)&dinv[c4];
        float4 v = *(float4*)&A[i * STR + c4];
        v.x *= di * dj.x; v.y *= di * dj.y; v.z *= di * dj.z; v.w *= di * dj.w;
        *(float4*)&A[i * STR + c4] = v;
        if (i == NREG && c4 < 96) *(float4*)&arow[c4] = v;
    }
    __syncthreads();

    // ---- 4.5) in-place fp32 -> packed (lo<<16|hi) bf16 pair ----
    for (int m = t; m < JROWS * (STR / 4); m += 256) {
        int i = m / (STR / 4);
        int c4 = (m - i * (STR / 4)) * 4;
        float4 v = *(float4*)&A[i * STR + c4];
        uint4 p;
        p.x = pack_hl(v.x); p.y = pack_hl(v.y);
        p.z = pack_hl(v.z); p.w = pack_hl(v.w);
        *(uint4*)&A[i * STR + c4] = p;
    }
    __syncthreads();

    // ---- 5) MFMA: wave w owns n-tiles w*4..w*4+3; A from LDS via perm unpack ----
    {
        const int w = t >> 6, lane = t & 63;
        const int lrow = lane & 15, lkg = lane >> 4;
        const unsigned int* Au = (const unsigned int*)A;

        bf16x8 whi_r[4][3], wlo_r[4][3];
        #pragma unroll
        for (int nt = 0; nt < 4; ++nt)
            #pragma unroll
            for (int ks = 0; ks < 3; ++ks) {
                int idx = (((w * 4 + nt) * 3 + ks) * 64 + lane) * 8;
                whi_r[nt][ks] = *(const bf16x8*)(Whi + idx);
                wlo_r[nt][ks] = *(const bf16x8*)(Wlo + idx);
            }

        float sp[4] = {0.f, 0.f, 0.f, 0.f};

        #pragma unroll 1
        for (int m = 0; m < 6; ++m) {
            bf16x8 ahi[3], alo[3];
            #pragma unroll
            for (int ks = 0; ks < 3; ++ks) {
                const uint4* src = (const uint4*)(Au + (m * 16 + lrow) * STR + ks * 32 + lkg * 8);
                uint4 a0 = src[0];
                uint4 a1 = src[1];
                u32x4v hw, lw;
                hw[0] = __builtin_amdgcn_perm(a0.y, a0.x, 0x05040100u);
                hw[1] = __builtin_amdgcn_perm(a0.w, a0.z, 0x05040100u);
                hw[2] = __builtin_amdgcn_perm(a1.y, a1.x, 0x05040100u);
                hw[3] = __builtin_amdgcn_perm(a1.w, a1.z, 0x05040100u);
                lw[0] = __builtin_amdgcn_perm(a0.y, a0.x, 0x07060302u);
                lw[1] = __builtin_amdgcn_perm(a0.w, a0.z, 0x07060302u);
                lw[2] = __builtin_amdgcn_perm(a1.y, a1.x, 0x07060302u);
                lw[3] = __builtin_amdgcn_perm(a1.w, a1.z, 0x07060302u);
                ahi[ks] = __builtin_bit_cast(bf16x8, hw);
                alo[ks] = __builtin_bit_cast(bf16x8, lw);
            }
            float aj[4];
            #pragma unroll
            for (int ri = 0; ri < 4; ++ri)
                aj[ri] = arow[m * 16 + lkg * 4 + ri];

            f32x4 acc[4];
            #pragma unroll
            for (int nt = 0; nt < 4; ++nt) acc[nt] = (f32x4){0.f, 0.f, 0.f, 0.f};

            #pragma unroll
            for (int ks = 0; ks < 3; ++ks)
                #pragma unroll
                for (int nt = 0; nt < 4; ++nt) {
                    acc[nt] = __builtin_amdgcn_mfma_f32_16x16x32_bf16(ahi[ks], whi_r[nt][ks], acc[nt], 0, 0, 0);
                    acc[nt] = __builtin_amdgcn_mfma_f32_16x16x32_bf16(ahi[ks], wlo_r[nt][ks], acc[nt], 0, 0, 0);
                    acc[nt] = __builtin_amdgcn_mfma_f32_16x16x32_bf16(alo[ks], whi_r[nt][ks], acc[nt], 0, 0, 0);
                }
            #pragma unroll
            for (int nt = 0; nt < 4; ++nt)
                #pragma unroll
                for (int ri = 0; ri < 4; ++ri)
                    sp[nt] = fmaf(aj[ri], fmaxf(acc[nt][ri], 0.f), sp[nt]);
        }

        #pragma unroll
        for (int nt = 0; nt < 4; ++nt) {
            float s = sp[nt];
            s += __shfl_xor(s, 16);
            s += __shfl_xor(s, 32);
            if (lane < 16)
                svec_out[(size_t)b * 256 + (w * 4 + nt) * 16 + lrow] = s;
        }
    }
}

// ================= kernel 3: batched fp32 MLP tail (coalesced weights) =================
__global__ __launch_bounds__(512)
void k3_tail(const float* __restrict__ svec,   // [B][256]
             const float* __restrict__ W2T,    // [256][256]
             const float* __restrict__ Wo1T,   // [256][128]
             const float* __restrict__ bo1,
             const float* __restrict__ Wo2,    // [2][128]
             const float* __restrict__ bo2,
             float* __restrict__ out, int B)
{
    __shared__ __align__(16) float Sl[32][260];   // S-tile, then reused as fc1 buffer
    __shared__ __align__(16) float Pl[32][260];   // pooled (256 channels)

    const int t = threadIdx.x;
    const int b0 = blockIdx.x * 32;

    for (int idx = t; idx < 2048; idx += 512) {
        int row = idx >> 6, c4 = (idx & 63) << 2;
        float4 v = make_float4(0.f, 0.f, 0.f, 0.f);
        if (b0 + row < B) v = *(const float4*)&svec[(size_t)(b0 + row) * 256 + c4];
        *(float4*)&Sl[row][c4] = v;
    }
    __syncthreads();

    // ---- pooled[b][g] = sum_h S[b][h] * W2T[h][g]; thread: 4 b x 4 g ----
    {
        const int bq = t >> 6, gq = t & 63;
        float acc[4][4];
        #pragma unroll
        for (int i = 0; i < 4; ++i)
            #pragma unroll
            for (int j = 0; j < 4; ++j) acc[i][j] = 0.f;
        #pragma unroll 2
        for (int h = 0; h < 256; ++h) {
            float4 wv = *(const float4*)&W2T[h * 256 + gq * 4];   // coalesced
            float s0 = Sl[bq * 4 + 0][h];
            float s1 = Sl[bq * 4 + 1][h];
            float s2 = Sl[bq * 4 + 2][h];
            float s3 = Sl[bq * 4 + 3][h];
            acc[0][0] = fmaf(s0, wv.x, acc[0][0]); acc[0][1] = fmaf(s0, wv.y, acc[0][1]);
            acc[0][2] = fmaf(s0, wv.z, acc[0][2]); acc[0][3] = fmaf(s0, wv.w, acc[0][3]);
            acc[1][0] = fmaf(s1, wv.x, acc[1][0]); acc[1][1] = fmaf(s1, wv.y, acc[1][1]);
            acc[1][2] = fmaf(s1, wv.z, acc[1][2]); acc[1][3] = fmaf(s1, wv.w, acc[1][3]);
            acc[2][0] = fmaf(s2, wv.x, acc[2][0]); acc[2][1] = fmaf(s2, wv.y, acc[2][1]);
            acc[2][2] = fmaf(s2, wv.z, acc[2][2]); acc[2][3] = fmaf(s2, wv.w, acc[2][3]);
            acc[3][0] = fmaf(s3, wv.x, acc[3][0]); acc[3][1] = fmaf(s3, wv.y, acc[3][1]);
            acc[3][2] = fmaf(s3, wv.z, acc[3][2]); acc[3][3] = fmaf(s3, wv.w, acc[3][3]);
        }
        #pragma unroll
        for (int i = 0; i < 4; ++i)
            #pragma unroll
            for (int j = 0; j < 4; ++j)
                Pl[bq * 4 + i][gq * 4 + j] = acc[i][j];
    }
    __syncthreads();

    // ---- fc1[b][f] = relu(sum_h P[b][h] * Wo1T[h][f] + bo1[f]); thread: 4 b x 2 f ----
    float* Fl = &Sl[0][0];                       // reuse S buffer, stride 132
    {
        const int bq = t >> 6, fq = t & 63;
        float acc[4][2];
        #pragma unroll
        for (int i = 0; i < 4; ++i) { acc[i][0] = 0.f; acc[i][1] = 0.f; }
        #pragma unroll 2
        for (int h = 0; h < 256; ++h) {
            float2 wv = *(const float2*)&Wo1T[h * 128 + fq * 2];  // coalesced
            float s0 = Pl[bq * 4 + 0][h];
            float s1 = Pl[bq * 4 + 1][h];
            float s2 = Pl[bq * 4 + 2][h];
            float s3 = Pl[bq * 4 + 3][h];
            acc[0][0] = fmaf(s0, wv.x, acc[0][0]); acc[0][1] = fmaf(s0, wv.y, acc[0][1]);
            acc[1][0] = fmaf(s1, wv.x, acc[1][0]); acc[1][1] = fmaf(s1, wv.y, acc[1][1]);
            acc[2][0] = fmaf(s2, wv.x, acc[2][0]); acc[2][1] = fmaf(s2, wv.y, acc[2][1]);
            acc[3][0] = fmaf(s3, wv.x, acc[3][0]); acc[3][1] = fmaf(s3, wv.y, acc[3][1]);
        }
        float b0f = bo1[fq * 2 + 0];
        float b1f = bo1[fq * 2 + 1];
        __syncthreads();   // Sl reads done before overwrite as Fl
        #pragma unroll
        for (int i = 0; i < 4; ++i) {
            Fl[(bq * 4 + i) * 132 + fq * 2 + 0] = fmaxf(acc[i][0] + b0f, 0.f);
            Fl[(bq * 4 + i) * 132 + fq * 2 + 1] = fmaxf(acc[i][1] + b1f, 0.f);
        }
    }
    __syncthreads();

    // ---- out[b][o] = Wo2[o] . fc1[b] + bo2[o] ----
    if (t < 256) {
        int b = t >> 3, o = (t >> 2) & 1, q = t & 3;
        const float* wo = Wo2 + o * F1 + q * 32;
        const float* fv = Fl + b * 132 + q * 32;
        float p = 0.f;
        #pragma unroll
        for (int k = 0; k < 32; ++k) p = fmaf(wo[k], fv[k], p);
        p += __shfl_xor(p, 1);
        p += __shfl_xor(p, 2);
        if (q == 0 && b0 + b < B) out[(size_t)(b0 + b) * 2 + o] = p + bo2[o];
    }
}

// ================= fallback: R9 monolithic kernel (ws too small) =================
__global__ __launch_bounds__(256)
void gcn_mono(const float* __restrict__ coh, const __bf16* __restrict__ Whi,
              const __bf16* __restrict__ Wlo, const int* __restrict__ ptab,
              const float* __restrict__ W2, const float* __restrict__ Wo1,
              const float* __restrict__ bo1, const float* __restrict__ Wo2,
              const float* __restrict__ bo2, float* __restrict__ out)
{
    __shared__ __align__(16) float A[JROWS * STR];
    __shared__ __align__(16) float svec_fc1[H1];
    __shared__ __align__(16) float pooled_dinv[H2];
    __shared__ __align__(16) float arow[96];
    float* dinv = pooled_dinv;
    float* pooled = pooled_dinv;
    const int b = blockIdx.x;
    const int t = threadIdx.x;
    const float* cb = coh + (size_t)b * NPAIR;

    for (int m = t; m < JROWS * 24; m += 256) {
        int i = m / 24, g = m - i * 24;
        *(float4*)&A[i * STR + g * 4] = make_float4(0.f, 0.f, 0.f, 0.f);
    }
    __syncthreads();
    for (int m = t; m < NPAIR; m += 256) {
        int p = ptab[m];
        int i = p >> 7, j = p & 127;
        float v = cb[m];
        A[i * STR + j] = v;
        A[j * STR + i] = v;
    }
    if (t < NN) {
        A[t * STR + t] = 1.0f;
        if (t < NREG) { A[NREG * STR + t] = 1.0f; A[t * STR + NREG] = 1.0f; }
    }
    __syncthreads();
    if (t < 256) dinv[t] = 0.0f;
    __syncthreads();
    if (t < NN) {
        const float4* row = (const float4*)&A[t * STR];
        float sx = 0.f, sy = 0.f, sz = 0.f, sw = 0.f;
        #pragma unroll
        for (int q = 0; q < 24; ++q) { float4 v = row[q]; sx += v.x; sy += v.y; sz += v.z; sw += v.w; }
        dinv[t] = 1.0f / sqrtf((sx + sy) + (sz + sw));
    }
    __syncthreads();
    for (int m = t; m < JROWS * 24; m += 256) {
        int i = m / 24;
        int c4 = (m - i * 24) * 4;
        float di = dinv[i];
        float4 dj = *(const float4*)&dinv[c4];
        float4 v = *(float4*)&A[i * STR + c4];
        v.x *= di * dj.x; v.y *= di * dj.y; v.z *= di * dj.z; v.w *= di * dj.w;
        *(float4*)&A[i * STR + c4] = v;
        if (i == NREG) *(float4*)&arow[c4] = v;
    }
    __syncthreads();
    for (int m = t; m < JROWS * 24; m += 256) {
        int i = m / 24;
        int c4 = (m - i * 24) * 4;
        float4 v = *(float4*)&A[i * STR + c4];
        uint4 p;
        p.x = pack_hl(v.x); p.y = pack_hl(v.y); p.z = pack_hl(v.z); p.w = pack_hl(v.w);
        *(uint4*)&A[i * STR + c4] = p;
    }
    __syncthreads();
    {
        const int w = t >> 6, lane = t & 63;
        const int lrow = lane & 15, lkg = lane >> 4;
        const unsigned int* Au = (const unsigned int*)A;
        bf16x8 whi_r[4][3], wlo_r[4][3];
        #pragma unroll
        for (int nt = 0; nt < 4; ++nt)
            #pragma unroll
            for (int ks = 0; ks < 3; ++ks) {
                int idx = (((w * 4 + nt) * 3 + ks) * 64 + lane) * 8;
                whi_r[nt][ks] = *(const bf16x8*)(Whi + idx);
                wlo_r[nt][ks] = *(const bf16x8*)(Wlo + idx);
            }
        float sp[4] = {0.f, 0.f, 0.f, 0.f};
        #pragma unroll 1
        for (int m = 0; m < 6; ++m) {
            bf16x8 ahi[3], alo[3];
            #pragma unroll
            for (int ks = 0; ks < 3; ++ks) {
                const uint4* src = (const uint4*)(Au + (m * 16 + lrow) * STR + ks * 32 + lkg * 8);
                uint4 a0 = src[0];
                uint4 a1 = src[1];
                u32x4v hw, lw;
                hw[0] = __builtin_amdgcn_perm(a0.y, a0.x, 0x05040100u);
                hw[1] = __builtin_amdgcn_perm(a0.w, a0.z, 0x05040100u);
                hw[2] = __builtin_amdgcn_perm(a1.y, a1.x, 0x05040100u);
                hw[3] = __builtin_amdgcn_perm(a1.w, a1.z, 0x05040100u);
                lw[0] = __builtin_amdgcn_perm(a0.y, a0.x, 0x07060302u);
                lw[1] = __builtin_amdgcn_perm(a0.w, a0.z, 0x07060302u);
                lw[2] = __builtin_amdgcn_perm(a1.y, a1.x, 0x07060302u);
                lw[3] = __builtin_amdgcn_perm(a1.w, a1.z, 0x07060302u);
                ahi[ks] = __builtin_bit_cast(bf16x8, hw);
                alo[ks] = __builtin_bit_cast(bf16x8, lw);
            }
            float aj[4];
            #pragma unroll
            for (int ri = 0; ri < 4; ++ri) aj[ri] = arow[m * 16 + lkg * 4 + ri];
            f32x4 acc[4];
            #pragma unroll
            for (int nt = 0; nt < 4; ++nt) acc[nt] = (f32x4){0.f, 0.f, 0.f, 0.f};
            #pragma unroll
            for (int ks = 0; ks < 3; ++ks)
                #pragma unroll
                for (int nt = 0; nt < 4; ++nt) {
                    acc[nt] = __builtin_amdgcn_mfma_f32_16x16x32_bf16(ahi[ks], whi_r[nt][ks], acc[nt], 0, 0, 0);
                    acc[nt] = __builtin_amdgcn_mfma_f32_16x16x32_bf16(ahi[ks], wlo_r[nt][ks], acc[nt], 0, 0, 0);
                    acc[nt] = __builtin_amdgcn_mfma_f32_16x16x32_bf16(alo[ks], whi_r[nt][ks], acc[nt], 0, 0, 0);
                }
            #pragma unroll
            for (int nt = 0; nt < 4; ++nt)
                #pragma unroll
                for (int ri = 0; ri < 4; ++ri)
                    sp[nt] = fmaf(aj[ri], fmaxf(acc[nt][ri], 0.f), sp[nt]);
        }
        __syncthreads();
        #pragma unroll
        for (int nt = 0; nt < 4; ++nt) {
            float s = sp[nt];
            s += __shfl_xor(s, 16);
            s += __shfl_xor(s, 32);
            if (lane < 16) svec_fc1[(w * 4 + nt) * 16 + lrow] = s;
        }
    }
    __syncthreads();
    {
        const float* w2r = W2 + t * H1;
        float p0 = 0.f, p1 = 0.f, p2 = 0.f, p3 = 0.f;
        #pragma unroll 8
        for (int qq = 0; qq < H1 / 4; ++qq) {
            float4 sv = ((const float4*)svec_fc1)[qq];
            float4 wv4 = *(const float4*)&w2r[qq * 4];
            p0 = fmaf(sv.x, wv4.x, p0); p1 = fmaf(sv.y, wv4.y, p1);
            p2 = fmaf(sv.z, wv4.z, p2); p3 = fmaf(sv.w, wv4.w, p3);
        }
        float pr = (p0 + p1) + (p2 + p3);
        __syncthreads();
        pooled[t] = pr;
    }
    __syncthreads();
    {
        float fr = 0.f;
        if (t < F1) {
            const float* wo1r = Wo1 + t * H2;
            float p0 = bo1[t], p1 = 0.f, p2 = 0.f, p3 = 0.f;
            #pragma unroll 8
            for (int qq = 0; qq < H2 / 4; ++qq) {
                float4 pv = ((const float4*)pooled)[qq];
                float4 wv4 = *(const float4*)&wo1r[qq * 4];
                p0 = fmaf(pv.x, wv4.x, p0); p1 = fmaf(pv.y, wv4.y, p1);
                p2 = fmaf(pv.z, wv4.z, p2); p3 = fmaf(pv.w, wv4.w, p3);
            }
            fr = fmaxf((p0 + p1) + (p2 + p3), 0.f);
        }
        __syncthreads();
        if (t < F1) svec_fc1[t] = fr;
    }
    __syncthreads();
    if (t < 64) {
        int o = t & 1;
        int f0 = t >> 1;
        const float* wo2r = Wo2 + o * F1;
        float p = 0.f;
        #pragma unroll
        for (int s = 0; s < 4; ++s) p = fmaf(wo2r[f0 + 32 * s], svec_fc1[f0 + 32 * s], p);
        p += __shfl_xor(p, 2); p += __shfl_xor(p, 4); p += __shfl_xor(p, 8);
        p += __shfl_xor(p, 16); p += __shfl_xor(p, 32);
        if (t < 2) out[(size_t)b * 2 + t] = p + bo2[t];
    }
}

extern "C" void kernel_launch(void* const* d_in, const int* in_sizes, int n_in,
                              void* d_out, int out_size, void* d_ws, size_t ws_size,
                              hipStream_t stream) {
    const float* coh = (const float*)d_in[0];
    const float* W1  = (const float*)d_in[1];
    const float* W2  = (const float*)d_in[2];
    const float* Wo1 = (const float*)d_in[3];
    const float* bo1 = (const float*)d_in[4];
    const float* Wo2 = (const float*)d_in[5];
    const float* bo2 = (const float*)d_in[6];
    float* outp = (float*)d_out;

    const int B = in_sizes[0] / NPAIR;            // 4096

    // ws layout
    __bf16* Whi  = (__bf16*)d_ws;                               // 49152 B
    __bf16* Wlo  = Whi + 24576;                                 // 49152 B
    int*    ptab = (int*)((char*)d_ws + 98304);                 // -> pad to 114688
    float*  W2T  = (float*)((char*)d_ws + 114688);              // 262144 B
    float*  Wo1T = (float*)((char*)d_ws + 376832);              // 131072 B
    float*  svecw= (float*)((char*)d_ws + 507904);              // B*1024 B
    const size_t need = 507904 + (size_t)B * 1024;

    prep<<<256, 256, 0, stream>>>(W1, W2, Wo1, Whi, Wlo, ptab, W2T, Wo1T);

    if (ws_size >= need) {
        mk_build_gemm<<<B, 256, 0, stream>>>(coh, ptab, Whi, Wlo, svecw);
        k3_tail<<<(B + 31) / 32, 512, 0, stream>>>(svecw, W2T, Wo1T, bo1, Wo2, bo2, outp, B);
    } else {
        gcn_mono<<<B, 256, 0, stream>>>(coh, Whi, Wlo, ptab, W2, Wo1, bo1, Wo2, bo2, outp);
    }
}

// Round 15
// 165.659 us; speedup vs baseline: 1.6675x; 1.0111x over previous
//
#include <hip/hip_runtime.h>
#include <hip/hip_bf16.h>
#include <math.h>

#define NREG 90
#define NN 91
#define JROWS 96
#define STR 100           // fp32 A LDS stride (words)
#define NPAIR 4005
#define H1 256
#define H2 256
#define F1 128

typedef __bf16 bf16x8 __attribute__((ext_vector_type(8)));
typedef float  f32x4  __attribute__((ext_vector_type(4)));
typedef unsigned int u32x4v __attribute__((ext_vector_type(4)));

__device__ __forceinline__ unsigned int pack_hl(float f) {
    __bf16 h = (__bf16)f;
    __bf16 l = (__bf16)(f - (float)h);
    unsigned short hb = __builtin_bit_cast(unsigned short, h);
    unsigned short lb = __builtin_bit_cast(unsigned short, l);
    return ((unsigned int)lb << 16) | (unsigned int)hb;
}

// ---- one-shot prep: W1 frags + pair table + transposed tail weights ----
__global__ void prep(const float* __restrict__ W1, const float* __restrict__ W2,
                     const float* __restrict__ Wo1,
                     __bf16* __restrict__ Whi, __bf16* __restrict__ Wlo,
                     int* __restrict__ ptab,
                     float* __restrict__ W2T, float* __restrict__ Wo1T) {
    int t = blockIdx.x * 256 + threadIdx.x;       // 0..65535
    if (t < 24576) {
        int e  = t & 7;
        int ln = (t >> 3) & 63;
        int g  = t >> 9;
        int nt = g / 3;
        int ks = g - nt * 3;
        int h = nt * 16 + (ln & 15);
        int k = ks * 32 + (ln >> 4) * 8 + e;
        float v = (k < NN) ? W1[h * NN + k] : 0.0f;
        __bf16 hb = (__bf16)v;
        __bf16 lb = (__bf16)(v - (float)hb);
        Whi[t] = hb;
        Wlo[t] = lb;
    }
    if (t < 65536)                                  // W2T[h][g] = W2[g][h]
        W2T[t] = W2[(t & 255) * 256 + (t >> 8)];
    if (t < 32768)                                  // Wo1T[h][f] = Wo1[f][h]
        Wo1T[t] = Wo1[(t & 127) * 256 + (t >> 7)];
    if (t < NPAIR) {
        float disc = 32041.0f - 8.0f * (float)t;
        int i = (int)floorf((179.0f - sqrtf(disc)) * 0.5f);
        if (i < 0) i = 0;
        while (i > 0 && t < i * (179 - i) / 2) --i;
        while (t >= (i + 1) * (178 - i) / 2) ++i;
        int j = i + 1 + (t - i * (179 - i) / 2);
        ptab[t] = (i << 7) | j;
    }
}

// ========== merged kernel: build A_hat + pack + MFMA z-stage -> svec ==========
__global__ __launch_bounds__(256)
void mk_build_gemm(const float* __restrict__ coh,    // [B, 4005]
                   const int*   __restrict__ ptab,
                   const __bf16* __restrict__ Whi,   // [16][3][64][8]
                   const __bf16* __restrict__ Wlo,
                   float* __restrict__ svec_out)     // [B][256]
{
    __shared__ __align__(16) float A[JROWS * STR];   // 38400 B
    __shared__ __align__(16) float dinv[128];
    __shared__ __align__(16) float arow[96];
    // ~39.3 KB -> 4 blocks/CU

    const int b = blockIdx.x;
    const int t = threadIdx.x;
    const float* cb = coh + (size_t)b * NPAIR;

    // ---- 1) zero A ----
    for (int m = t; m < JROWS * (STR / 4); m += 256)
        ((float4*)A)[m] = make_float4(0.f, 0.f, 0.f, 0.f);
    if (t < 128) dinv[t] = 0.0f;
    __syncthreads();

    // ---- 2) scatter (int4 ptab, 4 coh elems/iter) + supernode + identity ----
    for (int m4 = t; m4 < NPAIR / 4; m4 += 256) {    // 1001 iters cover m = 0..4003
        int4 p4 = ((const int4*)ptab)[m4];
        float v0 = cb[4 * m4 + 0];
        float v1 = cb[4 * m4 + 1];
        float v2 = cb[4 * m4 + 2];
        float v3 = cb[4 * m4 + 3];
        int i0 = p4.x >> 7, j0 = p4.x & 127;
        int i1 = p4.y >> 7, j1 = p4.y & 127;
        int i2 = p4.z >> 7, j2 = p4.z & 127;
        int i3 = p4.w >> 7, j3 = p4.w & 127;
        A[i0 * STR + j0] = v0; A[j0 * STR + i0] = v0;
        A[i1 * STR + j1] = v1; A[j1 * STR + i1] = v1;
        A[i2 * STR + j2] = v2; A[j2 * STR + i2] = v2;
        A[i3 * STR + j3] = v3; A[j3 * STR + i3] = v3;
    }
    if (t == 0) {                                    // tail element m = 4004
        int p = ptab[NPAIR - 1];
        int i = p >> 7, j = p & 127;
        float v = cb[NPAIR - 1];
        A[i * STR + j] = v;
        A[j * STR + i] = v;
    }
    if (t < NN) {
        A[t * STR + t] = 1.0f;
        if (t < NREG) {
            A[NREG * STR + t] = 1.0f;
            A[t * STR + NREG] = 1.0f;
        }
    }
    __syncthreads();

    // ---- 3) degree^-1/2 ----
    if (t < NN) {
        const float4* row = (const float4*)&A[t * STR];
        float sx = 0.f, sy = 0.f, sz = 0.f, sw = 0.f;
        #pragma unroll
        for (int q = 0; q < STR / 4; ++q) {
            float4 v = row[q];
            sx += v.x; sy += v.y; sz += v.z; sw += v.w;
        }
        dinv[t] = 1.0f / sqrtf((sx + sy) + (sz + sw));
    }
    __syncthreads();

    // ---- 4) FUSED: scale + arow save + bf16-pair pack, single pass ----
    for (int m = t; m < JROWS * (STR / 4); m += 256) {
        int i = m / (STR / 4);
        int c4 = (m - i * (STR / 4)) * 4;
        float di = dinv[i];
        float4 dj = *(const float4*)&dinv[c4];
        float4 v = *(float4*)&A[i * STR + c4];
        v.x *= di * dj.x; v.y *= di * dj.y; v.z *= di * dj.z; v.w *= di * dj.w;
        if (i == NREG && c4 < 96) *(float4*)&arow[c4] = v;
        uint4 p;
        p.x = pack_hl(v.x); p.y = pack_hl(v.y);
        p.z = pack_hl(v.z); p.w = pack_hl(v.w);
        *(uint4*)&A[i * STR + c4] = p;
    }
    __syncthreads();

    // ---- 5) MFMA: wave w owns n-tiles w*4..w*4+3; full m-unroll for pipelining ----
    {
        const int w = t >> 6, lane = t & 63;
        const int lrow = lane & 15, lkg = lane >> 4;
        const unsigned int* Au = (const unsigned int*)A;

        bf16x8 whi_r[4][3], wlo_r[4][3];
        #pragma unroll
        for (int nt = 0; nt < 4; ++nt)
            #pragma unroll
            for (int ks = 0; ks < 3; ++ks) {
                int idx = (((w * 4 + nt) * 3 + ks) * 64 + lane) * 8;
                whi_r[nt][ks] = *(const bf16x8*)(Whi + idx);
                wlo_r[nt][ks] = *(const bf16x8*)(Wlo + idx);
            }

        float sp[4] = {0.f, 0.f, 0.f, 0.f};

        #pragma unroll
        for (int m = 0; m < 6; ++m) {
            bf16x8 ahi[3], alo[3];
            #pragma unroll
            for (int ks = 0; ks < 3; ++ks) {
                const uint4* src = (const uint4*)(Au + (m * 16 + lrow) * STR + ks * 32 + lkg * 8);
                uint4 a0 = src[0];
                uint4 a1 = src[1];
                u32x4v hw, lw;
                hw[0] = __builtin_amdgcn_perm(a0.y, a0.x, 0x05040100u);
                hw[1] = __builtin_amdgcn_perm(a0.w, a0.z, 0x05040100u);
                hw[2] = __builtin_amdgcn_perm(a1.y, a1.x, 0x05040100u);
                hw[3] = __builtin_amdgcn_perm(a1.w, a1.z, 0x05040100u);
                lw[0] = __builtin_amdgcn_perm(a0.y, a0.x, 0x07060302u);
                lw[1] = __builtin_amdgcn_perm(a0.w, a0.z, 0x07060302u);
                lw[2] = __builtin_amdgcn_perm(a1.y, a1.x, 0x07060302u);
                lw[3] = __builtin_amdgcn_perm(a1.w, a1.z, 0x07060302u);
                ahi[ks] = __builtin_bit_cast(bf16x8, hw);
                alo[ks] = __builtin_bit_cast(bf16x8, lw);
            }
            float aj[4];
            #pragma unroll
            for (int ri = 0; ri < 4; ++ri)
                aj[ri] = arow[m * 16 + lkg * 4 + ri];

            f32x4 acc[4];
            #pragma unroll
            for (int nt = 0; nt < 4; ++nt) acc[nt] = (f32x4){0.f, 0.f, 0.f, 0.f};

            #pragma unroll
            for (int ks = 0; ks < 3; ++ks)
                #pragma unroll
                for (int nt = 0; nt < 4; ++nt) {
                    acc[nt] = __builtin_amdgcn_mfma_f32_16x16x32_bf16(ahi[ks], whi_r[nt][ks], acc[nt], 0, 0, 0);
                    acc[nt] = __builtin_amdgcn_mfma_f32_16x16x32_bf16(ahi[ks], wlo_r[nt][ks], acc[nt], 0, 0, 0);
                    acc[nt] = __builtin_amdgcn_mfma_f32_16x16x32_bf16(alo[ks], whi_r[nt][ks], acc[nt], 0, 0, 0);
                }
            #pragma unroll
            for (int nt = 0; nt < 4; ++nt)
                #pragma unroll
                for (int ri = 0; ri < 4; ++ri)
                    sp[nt] = fmaf(aj[ri], fmaxf(acc[nt][ri], 0.f), sp[nt]);
        }

        #pragma unroll
        for (int nt = 0; nt < 4; ++nt) {
            float s = sp[nt];
            s += __shfl_xor(s, 16);
            s += __shfl_xor(s, 32);
            if (lane < 16)
                svec_out[(size_t)b * 256 + (w * 4 + nt) * 16 + lrow] = s;
        }
    }
}

// ================= kernel 3: batched fp32 MLP tail (coalesced weights) =================
__global__ __launch_bounds__(512)
void k3_tail(const float* __restrict__ svec,   // [B][256]
             const float* __restrict__ W2T,    // [256][256]
             const float* __restrict__ Wo1T,   // [256][128]
             const float* __restrict__ bo1,
             const float* __restrict__ Wo2,    // [2][128]
             const float* __restrict__ bo2,
             float* __restrict__ out, int B)
{
    __shared__ __align__(16) float Sl[32][260];   // S-tile, then reused as fc1 buffer
    __shared__ __align__(16) float Pl[32][260];   // pooled (256 channels)

    const int t = threadIdx.x;
    const int b0 = blockIdx.x * 32;

    for (int idx = t; idx < 2048; idx += 512) {
        int row = idx >> 6, c4 = (idx & 63) << 2;
        float4 v = make_float4(0.f, 0.f, 0.f, 0.f);
        if (b0 + row < B) v = *(const float4*)&svec[(size_t)(b0 + row) * 256 + c4];
        *(float4*)&Sl[row][c4] = v;
    }
    __syncthreads();

    // ---- pooled[b][g] = sum_h S[b][h] * W2T[h][g]; thread: 4 b x 4 g ----
    {
        const int bq = t >> 6, gq = t & 63;
        float acc[4][4];
        #pragma unroll
        for (int i = 0; i < 4; ++i)
            #pragma unroll
            for (int j = 0; j < 4; ++j) acc[i][j] = 0.f;
        #pragma unroll 2
        for (int h = 0; h < 256; ++h) {
            float4 wv = *(const float4*)&W2T[h * 256 + gq * 4];   // coalesced
            float s0 = Sl[bq * 4 + 0][h];
            float s1 = Sl[bq * 4 + 1][h];
            float s2 = Sl[bq * 4 + 2][h];
            float s3 = Sl[bq * 4 + 3][h];
            acc[0][0] = fmaf(s0, wv.x, acc[0][0]); acc[0][1] = fmaf(s0, wv.y, acc[0][1]);
            acc[0][2] = fmaf(s0, wv.z, acc[0][2]); acc[0][3] = fmaf(s0, wv.w, acc[0][3]);
            acc[1][0] = fmaf(s1, wv.x, acc[1][0]); acc[1][1] = fmaf(s1, wv.y, acc[1][1]);
            acc[1][2] = fmaf(s1, wv.z, acc[1][2]); acc[1][3] = fmaf(s1, wv.w, acc[1][3]);
            acc[2][0] = fmaf(s2, wv.x, acc[2][0]); acc[2][1] = fmaf(s2, wv.y, acc[2][1]);
            acc[2][2] = fmaf(s2, wv.z, acc[2][2]); acc[2][3] = fmaf(s2, wv.w, acc[2][3]);
            acc[3][0] = fmaf(s3, wv.x, acc[3][0]); acc[3][1] = fmaf(s3, wv.y, acc[3][1]);
            acc[3][2] = fmaf(s3, wv.z, acc[3][2]); acc[3][3] = fmaf(s3, wv.w, acc[3][3]);
        }
        #pragma unroll
        for (int i = 0; i < 4; ++i)
            #pragma unroll
            for (int j = 0; j < 4; ++j)
                Pl[bq * 4 + i][gq * 4 + j] = acc[i][j];
    }
    __syncthreads();

    // ---- fc1[b][f] = relu(sum_h P[b][h] * Wo1T[h][f] + bo1[f]); thread: 4 b x 2 f ----
    float* Fl = &Sl[0][0];                       // reuse S buffer, stride 132
    {
        const int bq = t >> 6, fq = t & 63;
        float acc[4][2];
        #pragma unroll
        for (int i = 0; i < 4; ++i) { acc[i][0] = 0.f; acc[i][1] = 0.f; }
        #pragma unroll 2
        for (int h = 0; h < 256; ++h) {
            float2 wv = *(const float2*)&Wo1T[h * 128 + fq * 2];  // coalesced
            float s0 = Pl[bq * 4 + 0][h];
            float s1 = Pl[bq * 4 + 1][h];
            float s2 = Pl[bq * 4 + 2][h];
            float s3 = Pl[bq * 4 + 3][h];
            acc[0][0] = fmaf(s0, wv.x, acc[0][0]); acc[0][1] = fmaf(s0, wv.y, acc[0][1]);
            acc[1][0] = fmaf(s1, wv.x, acc[1][0]); acc[1][1] = fmaf(s1, wv.y, acc[1][1]);
            acc[2][0] = fmaf(s2, wv.x, acc[2][0]); acc[2][1] = fmaf(s2, wv.y, acc[2][1]);
            acc[3][0] = fmaf(s3, wv.x, acc[3][0]); acc[3][1] = fmaf(s3, wv.y, acc[3][1]);
        }
        float b0f = bo1[fq * 2 + 0];
        float b1f = bo1[fq * 2 + 1];
        __syncthreads();   // Sl reads done before overwrite as Fl
        #pragma unroll
        for (int i = 0; i < 4; ++i) {
            Fl[(bq * 4 + i) * 132 + fq * 2 + 0] = fmaxf(acc[i][0] + b0f, 0.f);
            Fl[(bq * 4 + i) * 132 + fq * 2 + 1] = fmaxf(acc[i][1] + b1f, 0.f);
        }
    }
    __syncthreads();

    // ---- out[b][o] = Wo2[o] . fc1[b] + bo2[o] ----
    if (t < 256) {
        int b = t >> 3, o = (t >> 2) & 1, q = t & 3;
        const float* wo = Wo2 + o * F1 + q * 32;
        const float* fv = Fl + b * 132 + q * 32;
        float p = 0.f;
        #pragma unroll
        for (int k = 0; k < 32; ++k) p = fmaf(wo[k], fv[k], p);
        p += __shfl_xor(p, 1);
        p += __shfl_xor(p, 2);
        if (q == 0 && b0 + b < B) out[(size_t)(b0 + b) * 2 + o] = p + bo2[o];
    }
}

// ================= fallback: R9 monolithic kernel (ws too small) =================
__global__ __launch_bounds__(256)
void gcn_mono(const float* __restrict__ coh, const __bf16* __restrict__ Whi,
              const __bf16* __restrict__ Wlo, const int* __restrict__ ptab,
              const float* __restrict__ W2, const float* __restrict__ Wo1,
              const float* __restrict__ bo1, const float* __restrict__ Wo2,
              const float* __restrict__ bo2, float* __restrict__ out)
{
    __shared__ __align__(16) float A[JROWS * STR];
    __shared__ __align__(16) float svec_fc1[H1];
    __shared__ __align__(16) float pooled_dinv[H2];
    __shared__ __align__(16) float arow[96];
    float* dinv = pooled_dinv;
    float* pooled = pooled_dinv;
    const int b = blockIdx.x;
    const int t = threadIdx.x;
    const float* cb = coh + (size_t)b * NPAIR;

    for (int m = t; m < JROWS * 24; m += 256) {
        int i = m / 24, g = m - i * 24;
        *(float4*)&A[i * STR + g * 4] = make_float4(0.f, 0.f, 0.f, 0.f);
    }
    __syncthreads();
    for (int m = t; m < NPAIR; m += 256) {
        int p = ptab[m];
        int i = p >> 7, j = p & 127;
        float v = cb[m];
        A[i * STR + j] = v;
        A[j * STR + i] = v;
    }
    if (t < NN) {
        A[t * STR + t] = 1.0f;
        if (t < NREG) { A[NREG * STR + t] = 1.0f; A[t * STR + NREG] = 1.0f; }
    }
    __syncthreads();
    if (t < 256) dinv[t] = 0.0f;
    __syncthreads();
    if (t < NN) {
        const float4* row = (const float4*)&A[t * STR];
        float sx = 0.f, sy = 0.f, sz = 0.f, sw = 0.f;
        #pragma unroll
        for (int q = 0; q < 24; ++q) { float4 v = row[q]; sx += v.x; sy += v.y; sz += v.z; sw += v.w; }
        dinv[t] = 1.0f / sqrtf((sx + sy) + (sz + sw));
    }
    __syncthreads();
    for (int m = t; m < JROWS * 24; m += 256) {
        int i = m / 24;
        int c4 = (m - i * 24) * 4;
        float di = dinv[i];
        float4 dj = *(const float4*)&dinv[c4];
        float4 v = *(float4*)&A[i * STR + c4];
        v.x *= di * dj.x; v.y *= di * dj.y; v.z *= di * dj.z; v.w *= di * dj.w;
        *(float4*)&A[i * STR + c4] = v;
        if (i == NREG) *(float4*)&arow[c4] = v;
    }
    __syncthreads();
    for (int m = t; m < JROWS * 24; m += 256) {
        int i = m / 24;
        int c4 = (m - i * 24) * 4;
        float4 v = *(float4*)&A[i * STR + c4];
        uint4 p;
        p.x = pack_hl(v.x); p.y = pack_hl(v.y); p.z = pack_hl(v.z); p.w = pack_hl(v.w);
        *(uint4*)&A[i * STR + c4] = p;
    }
    __syncthreads();
    {
        const int w = t >> 6, lane = t & 63;
        const int lrow = lane & 15, lkg = lane >> 4;
        const unsigned int* Au = (const unsigned int*)A;
        bf16x8 whi_r[4][3], wlo_r[4][3];
        #pragma unroll
        for (int nt = 0; nt < 4; ++nt)
            #pragma unroll
            for (int ks = 0; ks < 3; ++ks) {
                int idx = (((w * 4 + nt) * 3 + ks) * 64 + lane) * 8;
                whi_r[nt][ks] = *(const bf16x8*)(Whi + idx);
                wlo_r[nt][ks] = *(const bf16x8*)(Wlo + idx);
            }
        float sp[4] = {0.f, 0.f, 0.f, 0.f};
        #pragma unroll 1
        for (int m = 0; m < 6; ++m) {
            bf16x8 ahi[3], alo[3];
            #pragma unroll
            for (int ks = 0; ks < 3; ++ks) {
                const uint4* src = (const uint4*)(Au + (m * 16 + lrow) * STR + ks * 32 + lkg * 8);
                uint4 a0 = src[0];
                uint4 a1 = src[1];
                u32x4v hw, lw;
                hw[0] = __builtin_amdgcn_perm(a0.y, a0.x, 0x05040100u);
                hw[1] = __builtin_amdgcn_perm(a0.w, a0.z, 0x05040100u);
                hw[2] = __builtin_amdgcn_perm(a1.y, a1.x, 0x05040100u);
                hw[3] = __builtin_amdgcn_perm(a1.w, a1.z, 0x05040100u);
                lw[0] = __builtin_amdgcn_perm(a0.y, a0.x, 0x07060302u);
                lw[1] = __builtin_amdgcn_perm(a0.w, a0.z, 0x07060302u);
                lw[2] = __builtin_amdgcn_perm(a1.y, a1.x, 0x07060302u);
                lw[3] = __builtin_amdgcn_perm(a1.w, a1.z, 0x07060302u);
                ahi[ks] = __builtin_bit_cast(bf16x8, hw);
                alo[ks] = __builtin_bit_cast(bf16x8, lw);
            }
            float aj[4];
            #pragma unroll
            for (int ri = 0; ri < 4; ++ri) aj[ri] = arow[m * 16 + lkg * 4 + ri];
            f32x4 acc[4];
            #pragma unroll
            for (int nt = 0; nt < 4; ++nt) acc[nt] = (f32x4){0.f, 0.f, 0.f, 0.f};
            #pragma unroll
            for (int ks = 0; ks < 3; ++ks)
                #pragma unroll
                for (int nt = 0; nt < 4; ++nt) {
                    acc[nt] = __builtin_amdgcn_mfma_f32_16x16x32_bf16(ahi[ks], whi_r[nt][ks], acc[nt], 0, 0, 0);
                    acc[nt] = __builtin_amdgcn_mfma_f32_16x16x32_bf16(ahi[ks], wlo_r[nt][ks], acc[nt], 0, 0, 0);
                    acc[nt] = __builtin_amdgcn_mfma_f32_16x16x32_bf16(alo[ks], whi_r[nt][ks], acc[nt], 0, 0, 0);
                }
            #pragma unroll
            for (int nt = 0; nt < 4; ++nt)
                #pragma unroll
                for (int ri = 0; ri < 4; ++ri)
                    sp[nt] = fmaf(aj[ri], fmaxf(acc[nt][ri], 0.f), sp[nt]);
        }
        __syncthreads();
        #pragma unroll
        for (int nt = 0; nt < 4; ++nt) {
            float s = sp[nt];
            s += __shfl_xor(s, 16);
            s += __shfl_xor(s, 32);
            if (lane < 16) svec_fc1[(w * 4 + nt) * 16 + lrow] = s;
        }
    }
    __syncthreads();
    {
        const float* w2r = W2 + t * H1;
        float p0 = 0.f, p1 = 0.f, p2 = 0.f, p3 = 0.f;
        #pragma unroll 8
        for (int qq = 0; qq < H1 / 4; ++qq) {
            float4 sv = ((const float4*)svec_fc1)[qq];
            float4 wv4 = *(const float4*)&w2r[qq * 4];
            p0 = fmaf(sv.x, wv4.x, p0); p1 = fmaf(sv.y, wv4.y, p1);
            p2 = fmaf(sv.z, wv4.z, p2); p3 = fmaf(sv.w, wv4.w, p3);
        }
        float pr = (p0 + p1) + (p2 + p3);
        __syncthreads();
        pooled[t] = pr;
    }
    __syncthreads();
    {
        float fr = 0.f;
        if (t < F1) {
            const float* wo1r = Wo1 + t * H2;
            float p0 = bo1[t], p1 = 0.f, p2 = 0.f, p3 = 0.f;
            #pragma unroll 8
            for (int qq = 0; qq < H2 / 4; ++qq) {
                float4 pv = ((const float4*)pooled)[qq];
                float4 wv4 = *(const float4*)&wo1r[qq * 4];
                p0 = fmaf(pv.x, wv4.x, p0); p1 = fmaf(pv.y, wv4.y, p1);
                p2 = fmaf(pv.z, wv4.z, p2); p3 = fmaf(pv.w, wv4.w, p3);
            }
            fr = fmaxf((p0 + p1) + (p2 + p3), 0.f);
        }
        __syncthreads();
        if (t < F1) svec_fc1[t] = fr;
    }
    __syncthreads();
    if (t < 64) {
        int o = t & 1;
        int f0 = t >> 1;
        const float* wo2r = Wo2 + o * F1;
        float p = 0.f;
        #pragma unroll
        for (int s = 0; s < 4; ++s) p = fmaf(wo2r[f0 + 32 * s], svec_fc1[f0 + 32 * s], p);
        p += __shfl_xor(p, 2); p += __shfl_xor(p, 4); p += __shfl_xor(p, 8);
        p += __shfl_xor(p, 16); p += __shfl_xor(p, 32);
        if (t < 2) out[(size_t)b * 2 + t] = p + bo2[t];
    }
}

extern "C" void kernel_launch(void* const* d_in, const int* in_sizes, int n_in,
                              void* d_out, int out_size, void* d_ws, size_t ws_size,
                              hipStream_t stream) {
    const float* coh = (const float*)d_in[0];
    const float* W1  = (const float*)d_in[1];
    const float* W2  = (const float*)d_in[2];
    const float* Wo1 = (const float*)d_in[3];
    const float* bo1 = (const float*)d_in[4];
    const float* Wo2 = (const float*)d_in[5];
    const float* bo2 = (const float*)d_in[6];
    float* outp = (float*)d_out;

    const int B = in_sizes[0] / NPAIR;            // 4096

    // ws layout
    __bf16* Whi  = (__bf16*)d_ws;                               // 49152 B
    __bf16* Wlo  = Whi + 24576;                                 // 49152 B
    int*    ptab = (int*)((char*)d_ws + 98304);                 // -> pad to 114688
    float*  W2T  = (float*)((char*)d_ws + 114688);              // 262144 B
    float*  Wo1T = (float*)((char*)d_ws + 376832);              // 131072 B
    float*  svecw= (float*)((char*)d_ws + 507904);              // B*1024 B
    const size_t need = 507904 + (size_t)B * 1024;

    prep<<<256, 256, 0, stream>>>(W1, W2, Wo1, Whi, Wlo, ptab, W2T, Wo1T);

    if (ws_size >= need) {
        mk_build_gemm<<<B, 256, 0, stream>>>(coh, ptab, Whi, Wlo, svecw);
        k3_tail<<<(B + 31) / 32, 512, 0, stream>>>(svecw, W2T, Wo1T, bo1, Wo2, bo2, outp, B);
    } else {
        gcn_mono<<<B, 256, 0, stream>>>(coh, Whi, Wlo, ptab, W2, Wo1, bo1, Wo2, bo2, outp);
    }
}